// Round 2
// 5103.938 us; speedup vs baseline: 1.2171x; 1.2171x over previous
//
#include <hip/hip_runtime.h>

// ---------------------------------------------------------------------------
// Problem constants
// ---------------------------------------------------------------------------
#define Bv 8
#define Sv 256
#define Hv 16
#define Dv 64
#define LR 0.1f
#define SCALE (2.0f / 8192.0f)   // dLoss/dpred scale: 2/(B*H*D)

using bf16x8 = __attribute__((ext_vector_type(8))) short;
using bf16x4 = __attribute__((ext_vector_type(4))) short;
using f32x4  = __attribute__((ext_vector_type(4))) float;
#define MFMA16(A, B, C) __builtin_amdgcn_mfma_f32_16x16x32_bf16(A, B, C, 0, 0, 0)

// ---------------------------------------------------------------------------
// LDS layout (ushort units for bf16 planes, float units for fp32 areas)
// Weight/row planes: pitch 136 ushort = 272 B (hi[64] | lo[64] | pad[8]).
// T arrays: pitch 16 ushort = 32 B (hi[8] | lo[8]).
// G = Lw@Lw^T replaces LwT (F3+B1 fused); TGp (tg bf16 planes) replaces DPp.
// ---------------------------------------------------------------------------
constexpr int U_W1T = 0;          // [f][d] planes, 64x136
constexpr int U_W2T = 8704;      // [d][f]
constexpr int U_W2R = 17408;     // [f][d]
constexpr int U_G   = 26112;     // [d][d']  (symmetric, static)
constexpr int U_LwR = 34816;     // [d][e]   (static)
constexpr int U_K   = 43520;     // [b pad16][d] 16x136
constexpr int U_H   = 45696;     // [b][f]
constexpr int U_Z   = 47872;     // [b][d]
constexpr int U_TG  = 50048;     // [b pad16][e] target planes
constexpr int U_DO  = 52224;     // [b][d]
constexpr int U_KT  = 54400;     // [d][b] 64x16
constexpr int U_HT  = 55424;     // [f][b]
constexpr int U_DOT = 56448;     // [d][b]
constexpr int U_DAT = 57472;     // [f][b]
constexpr int F_BASE = 29248;    // = 58496/2
constexpr int F_O   = F_BASE;        // o / dz shared, [8][68]
constexpr int F_XH  = F_BASE + 544;
constexpr int F_GD  = F_XH + 544;
constexpr int F_TGL = F_GD + 544;    // tgl - c1, [8][68]
constexpr int F_B1  = F_TGL + 544;
constexpr int F_B2  = F_B1 + 64;
constexpr int F_LG  = F_B2 + 64;
constexpr int F_LB  = F_LG + 64;
constexpr int F_C1  = F_LB + 64;     // Lb @ Lw^T (static)
constexpr int F_TGm = F_C1 + 64;
constexpr int F_TBm = F_TGm + 64;
constexpr int F_RSTD = F_TBm + 64;
constexpr int LDS_BYTES = (F_RSTD + 8) * 4;   // 127520 B

// ---------------------------------------------------------------------------
// Helpers
// ---------------------------------------------------------------------------
__device__ __forceinline__ short bf_rn(float v) {
    unsigned u = __float_as_uint(v);
    unsigned r = u + 0x7fffu + ((u >> 16) & 1u);   // round-to-nearest-even
    return (short)(r >> 16);
}
__device__ __forceinline__ void cvt1(float v, short &hi, short &lo) {
    hi = bf_rn(v);
    float hf = __uint_as_float(((unsigned)(unsigned short)hi) << 16);
    lo = bf_rn(v - hf);
}
__device__ __forceinline__ float bf2f(short u) {
    return __uint_as_float(((unsigned)(unsigned short)u) << 16);
}
__device__ __forceinline__ unsigned pack2(short a, short b) {
    return ((unsigned)(unsigned short)a) | (((unsigned)(unsigned short)b) << 16);
}
// DPP-based 32-lane sum: 4 VALU-speed DPP adds + 1 cross-row swizzle.
// Replaces 5 dependent ds_swizzle round-trips (latency-bound kernel).
template <int CTRL>
__device__ __forceinline__ float dpp_add(float v) {
    int s = __builtin_amdgcn_update_dpp(0, __float_as_int(v), CTRL, 0xF, 0xF,
                                        true);
    return v + __int_as_float(s);
}
__device__ __forceinline__ float red32(float v) {
    v = dpp_add<0xB1>(v);    // quad_perm [1,0,3,2]  (xor 1)
    v = dpp_add<0x4E>(v);    // quad_perm [2,3,0,1]  (xor 2)
    v = dpp_add<0x124>(v);   // row_ror:4 (adds another quad-sum)
    v = dpp_add<0x128>(v);   // row_ror:8 (adds remaining half-row)
    v += __shfl_xor(v, 16);  // merge the two 16-rows of the 32-group
    return v;
}
__device__ __forceinline__ float fast_tanh(float u) {
    u = fminf(fmaxf(u, -10.f), 10.f);
    float e = __expf(2.0f * u);
    return (e - 1.0f) / (e + 1.0f);
}
__device__ __forceinline__ void gelu_both(float x, float &g, float &dg) {
    const float C0 = 0.7978845608028654f, A0 = 0.044715f;
    float x2 = x * x;
    float u = C0 * x * (1.0f + A0 * x2);
    float t = fast_tanh(u);
    g = 0.5f * x * (1.0f + t);
    float du = C0 * (1.0f + 3.0f * A0 * x2);
    dg = 0.5f * (1.0f + t) + 0.5f * x * (1.0f - t * t) * du;
}
__device__ __forceinline__ float gelu_f(float x) {
    const float C0 = 0.7978845608028654f, A0 = 0.044715f;
    float u = C0 * x * (1.0f + A0 * x * x);
    return 0.5f * x * (1.0f + fast_tanh(u));
}

// C[16x16 tile w] = A(16x64, row planes) @ B(64x64 via n-major planes)
// 4-MFMA split product (full hi/lo cross) for accuracy; two independent
// accumulation chains (kt) to halve MFMA dependency latency.
__device__ __forceinline__ f32x4 mm64(const unsigned short *Ap,
                                      const unsigned short *Bp,
                                      int w, int c, int q) {
    const unsigned short *ar = Ap + c * 136 + 8 * q;
    const unsigned short *br = Bp + (16 * w + c) * 136 + 8 * q;
    bf16x8 ah0 = *(const bf16x8 *)(ar);
    bf16x8 al0 = *(const bf16x8 *)(ar + 64);
    bf16x8 bh0 = *(const bf16x8 *)(br);
    bf16x8 bl0 = *(const bf16x8 *)(br + 64);
    bf16x8 ah1 = *(const bf16x8 *)(ar + 32);
    bf16x8 al1 = *(const bf16x8 *)(ar + 96);
    bf16x8 bh1 = *(const bf16x8 *)(br + 32);
    bf16x8 bl1 = *(const bf16x8 *)(br + 96);
    f32x4 x0 = {0.f, 0.f, 0.f, 0.f}, x1 = {0.f, 0.f, 0.f, 0.f};
    x0 = MFMA16(ah0, bh0, x0); x1 = MFMA16(ah1, bh1, x1);
    x0 = MFMA16(al0, bh0, x0); x1 = MFMA16(al1, bh1, x1);
    x0 = MFMA16(ah0, bl0, x0); x1 = MFMA16(ah1, bl1, x1);
    x0 = MFMA16(al0, bl0, x0); x1 = MFMA16(al1, bl1, x1);
    return x0 + x1;
}

// W(tile col n=16w+c) -= LR * X^T@Y ; X,Y given as T-arrays [64][b:8|8] bf16.
// Packed-K: one MFMA per 16-row block computes hh+lh+hl via K-chunks
// (q0: Xhi*Yhi, q1: Xlo*Yhi, q2: Xhi*Ylo, q3: 0) — was 3 MFMAs + idle lanes.
__device__ __forceinline__ void updW(const unsigned short *XT,
                                     const unsigned short *YT,
                                     unsigned short *WT,
                                     int w, int c, int q) {
    bf16x8 zf;
#pragma unroll
    for (int j = 0; j < 8; ++j) zf[j] = 0;
    bf16x8 b = zf;
    if (q < 2)
        b = *(const bf16x8 *)&YT[(16 * w + c) * 16];
    else if (q == 2)
        b = *(const bf16x8 *)&YT[(16 * w + c) * 16 + 8];
    f32x4 g[4];
#pragma unroll
    for (int mt = 0; mt < 4; ++mt) {
        bf16x8 a = *(const bf16x8 *)&XT[(16 * mt + c) * 16 + (q & 1) * 8];
        f32x4 z = {0.f, 0.f, 0.f, 0.f};
        g[mt] = MFMA16(a, b, z);
    }
#pragma unroll
    for (int mt = 0; mt < 4; ++mt) {
        unsigned short *ph = &WT[(16 * w + c) * 136 + 16 * mt + 4 * q];
        unsigned short *pl = ph + 64;
        bf16x4 oh = *(bf16x4 *)ph, ol = *(bf16x4 *)pl;
        bf16x4 nh, nl;
#pragma unroll
        for (int r = 0; r < 4; ++r) {
            float wv = bf2f(oh[r]) + bf2f(ol[r]) - LR * g[mt][r];
            short hh, ll;
            cvt1(wv, hh, ll);
            nh[r] = hh; nl[r] = ll;
        }
        *(bf16x4 *)ph = nh;
        *(bf16x4 *)pl = nl;
    }
}

// ---------------------------------------------------------------------------
// TTT scan kernel: one block (256 thr = 4 waves) per head
// ---------------------------------------------------------------------------
__global__ __launch_bounds__(256) void ttt_scan(
    const float *__restrict__ q_g, const float *__restrict__ k_g,
    const float *__restrict__ v_g, float *__restrict__ out_g,
    const float *__restrict__ fw_w1, const float *__restrict__ fw_b1,
    const float *__restrict__ fw_w2, const float *__restrict__ fw_b2,
    const float *__restrict__ fw_lng, const float *__restrict__ fw_lnb,
    const float *__restrict__ loss_w, const float *__restrict__ loss_bv,
    const float *__restrict__ ttt_gv, const float *__restrict__ ttt_bv) {
    extern __shared__ char smem[];
    unsigned short *us = (unsigned short *)smem;
    float *fs = (float *)smem;

    unsigned short *W1T = us + U_W1T, *W2T = us + U_W2T, *W2R = us + U_W2R;
    unsigned short *Gp = us + U_G, *LwR = us + U_LwR;
    unsigned short *Kp = us + U_K, *Hp = us + U_H, *Zp = us + U_Z;
    unsigned short *TGp = us + U_TG, *DOp = us + U_DO;
    unsigned short *KT = us + U_KT, *HT = us + U_HT;
    unsigned short *DOT = us + U_DOT, *DAT = us + U_DAT;
    float *o_s = fs + F_O, *xh_s = fs + F_XH, *gd_s = fs + F_GD;
    float *TGL = fs + F_TGL;
    float *b1_s = fs + F_B1, *b2_s = fs + F_B2, *lg_s = fs + F_LG;
    float *lb_s = fs + F_LB, *c1_s = fs + F_C1;
    float *tG_s = fs + F_TGm, *tB_s = fs + F_TBm, *rstd_s = fs + F_RSTD;

    const int h = blockIdx.x, tid = threadIdx.x;
    const int w = tid >> 6, lane = tid & 63, c = lane & 15, q = lane >> 4;

    // ---- init: split weights into bf16 hi/lo planes
    for (int i = tid; i < 4096; i += 256) {
        int r = i >> 6, cc = i & 63;
        short hi, lo;
        cvt1(fw_w1[h * 4096 + i], hi, lo);           // [d=r][f=cc]
        W1T[cc * 136 + r] = (unsigned short)hi;
        W1T[cc * 136 + 64 + r] = (unsigned short)lo;
        cvt1(fw_w2[h * 4096 + i], hi, lo);           // [f=r][d=cc]
        W2T[cc * 136 + r] = (unsigned short)hi;
        W2T[cc * 136 + 64 + r] = (unsigned short)lo;
        W2R[r * 136 + cc] = (unsigned short)hi;
        W2R[r * 136 + 64 + cc] = (unsigned short)lo;
        cvt1(loss_w[i], hi, lo);                     // [d=r][e=cc]
        LwR[r * 136 + cc] = (unsigned short)hi;
        LwR[r * 136 + 64 + cc] = (unsigned short)lo;
    }
    // zero pad rows 8..15 of the 5 activation row-plane arrays
    for (int i = tid; i < 5 * 8 * 128; i += 256) {
        int a = i / 128, u = i % 128;
        int arr = a >> 3, row = 8 + (a & 7);
        unsigned short *base = (arr == 0) ? Kp : (arr == 1) ? Hp
                              : (arr == 2) ? Zp : (arr == 3) ? TGp : DOp;
        base[row * 136 + u] = 0;
    }
    __syncthreads();
    // G = Lw @ Lw^T (static; fuses F3+B1 into one phase per step)
#pragma unroll 1
    for (int mt = 0; mt < 4; ++mt) {
        f32x4 g = mm64(LwR + 16 * 136 * mt, LwR, w, c, q);
#pragma unroll
        for (int r = 0; r < 4; ++r) {
            short hi, lo;
            cvt1(g[r], hi, lo);
            int dr = 16 * mt + 4 * q + r, dc = 16 * w + c;
            Gp[dr * 136 + dc] = (unsigned short)hi;
            Gp[dr * 136 + 64 + dc] = (unsigned short)lo;
        }
    }
    if (tid < 64) {
        b1_s[tid] = fw_b1[h * 64 + tid];
        b2_s[tid] = fw_b2[h * 64 + tid];
        lg_s[tid] = fw_lng[h * 64 + tid];
        lb_s[tid] = fw_lnb[h * 64 + tid];
        tG_s[tid] = ttt_gv[h * 64 + tid];
        tB_s[tid] = ttt_bv[h * 64 + tid];
        float c1 = 0.f;                      // c1[d] = sum_e Lb[e]*Lw[d,e]
        for (int e = 0; e < 64; ++e) c1 += loss_bv[e] * loss_w[tid * 64 + e];
        c1_s[tid] = c1;
    }
    __syncthreads();

    const int bb = tid >> 5, j0 = (tid & 31) * 2;

    // prefetch token 0
    float2 pk, pv, pq;
    {
        int idx = ((bb * Sv + 0) * Hv + h) * Dv + j0;
        pk = *(const float2 *)&k_g[idx];
        pv = *(const float2 *)&v_g[idx];
        pq = *(const float2 *)&q_g[idx];
    }

#pragma unroll 1
    for (int t = 0; t < Sv; ++t) {
        // ---- prologue: stage k (planes + kT) and target planes
        {
            short h0, l0, h1, l1;
            cvt1(pk.x, h0, l0);
            cvt1(pk.y, h1, l1);
            *(unsigned *)&Kp[bb * 136 + j0] = pack2(h0, h1);
            *(unsigned *)&Kp[bb * 136 + 64 + j0] = pack2(l0, l1);
            KT[j0 * 16 + bb] = (unsigned short)h0;
            KT[j0 * 16 + 8 + bb] = (unsigned short)l0;
            KT[(j0 + 1) * 16 + bb] = (unsigned short)h1;
            KT[(j0 + 1) * 16 + 8 + bb] = (unsigned short)l1;
            short t0h, t0l, t1h, t1l;
            cvt1(pv.x - pk.x, t0h, t0l);
            cvt1(pv.y - pk.y, t1h, t1l);
            *(unsigned *)&TGp[bb * 136 + j0] = pack2(t0h, t1h);
            *(unsigned *)&TGp[bb * 136 + 64 + j0] = pack2(t0l, t1l);
        }
        __syncthreads();

#pragma unroll 1
        for (int step = 0; step < 4; ++step) {
            // F1: h = gelu(k@W1 + b1)   [+ tgl = tg@Lw^T once per token]
            f32x4 acc = mm64(Kp, W1T, w, c, q);
            if (step == 0) {
                f32x4 a2 = mm64(TGp, LwR, w, c, q);
                if (q < 2) {
                    int col = 16 * w + c;
#pragma unroll
                    for (int r = 0; r < 4; ++r)
                        TGL[(4 * q + r) * 68 + col] = a2[r] - c1_s[col];
                }
            }
            if (q < 2) {
                float bias = b1_s[16 * w + c];
                bf16x4 hs, ls;
#pragma unroll
                for (int r = 0; r < 4; ++r) {
                    float g, dg;
                    gelu_both(acc[r] + bias, g, dg);
                    int row = 4 * q + r;
                    short hh, ll;
                    cvt1(g, hh, ll);
                    Hp[row * 136 + 16 * w + c] = (unsigned short)hh;
                    Hp[row * 136 + 64 + 16 * w + c] = (unsigned short)ll;
                    hs[r] = hh; ls[r] = ll;
                    gd_s[row * 68 + 16 * w + c] = dg;
                }
                *(bf16x4 *)&HT[(16 * w + c) * 16 + 4 * q] = hs;
                *(bf16x4 *)&HT[(16 * w + c) * 16 + 8 + 4 * q] = ls;
            }
            __syncthreads();
            // F2: o = h@W2 + b2
            acc = mm64(Hp, W2T, w, c, q);
            if (q < 2) {
                float bias = b2_s[16 * w + c];
#pragma unroll
                for (int r = 0; r < 4; ++r)
                    o_s[(4 * q + r) * 68 + 16 * w + c] = acc[r] + bias;
            }
            __syncthreads();
            // LN fwd (thread-mapped); xh kept in regs for LNb
            float xh0_r, xh1_r;
            {
                float2 xv = *(const float2 *)&o_s[bb * 68 + j0];
                float mu = red32(xv.x + xv.y) * (1.f / 64.f);
                float d0 = xv.x - mu, d1 = xv.y - mu;
                float var = red32(d0 * d0 + d1 * d1) * (1.f / 64.f);
                float rs = rsqrtf(var + 1e-5f);
                float xh0 = d0 * rs, xh1 = d1 * rs;
                float2 xw; xw.x = xh0; xw.y = xh1;
                *(float2 *)&xh_s[bb * 68 + j0] = xw;
                float z0 = xh0 * lg_s[j0] + lb_s[j0];
                float z1 = xh1 * lg_s[j0 + 1] + lb_s[j0 + 1];
                short h0, l0, h1, l1;
                cvt1(z0, h0, l0);
                cvt1(z1, h1, l1);
                *(unsigned *)&Zp[bb * 136 + j0] = pack2(h0, h1);
                *(unsigned *)&Zp[bb * 136 + 64 + j0] = pack2(l0, l1);
                if ((tid & 31) == 0) rstd_s[bb] = rs;
                xh0_r = xh0; xh1_r = xh1;
            }
            __syncthreads();
            // B1' (fused F3+B1): dz = SCALE * (z@G - (tgl - c1))
            acc = mm64(Zp, Gp, w, c, q);
            if (q < 2) {
                int col = 16 * w + c;
#pragma unroll
                for (int r = 0; r < 4; ++r) {
                    int row = 4 * q + r;
                    o_s[row * 68 + col] =
                        (acc[r] - TGL[row * 68 + col]) * SCALE;
                }
            }
            __syncthreads();
            // LN bwd (thread-mapped) -> do planes + doT
            {
                float2 dzv = *(const float2 *)&o_s[bb * 68 + j0];
                float dxh0 = dzv.x * lg_s[j0], dxh1 = dzv.y * lg_s[j0 + 1];
                float S1 = red32(dxh0 + dxh1) * (1.f / 64.f);
                float S2 = red32(dxh0 * xh0_r + dxh1 * xh1_r) * (1.f / 64.f);
                float rs = rstd_s[bb];
                float do0 = rs * (dxh0 - S1 - xh0_r * S2);
                float do1 = rs * (dxh1 - S1 - xh1_r * S2);
                short h0, l0, h1, l1;
                cvt1(do0, h0, l0);
                cvt1(do1, h1, l1);
                *(unsigned *)&DOp[bb * 136 + j0] = pack2(h0, h1);
                *(unsigned *)&DOp[bb * 136 + 64 + j0] = pack2(l0, l1);
                DOT[j0 * 16 + bb] = (unsigned short)h0;
                DOT[j0 * 16 + 8 + bb] = (unsigned short)l0;
                DOT[(j0 + 1) * 16 + bb] = (unsigned short)h1;
                DOT[(j0 + 1) * 16 + 8 + bb] = (unsigned short)l1;
            }
            __syncthreads();
            // B2: dh = do @ W2^T ; da = dh * gelu' -> DAT
            acc = mm64(DOp, W2R, w, c, q);
            if (q < 2) {
                bf16x4 hs, ls;
#pragma unroll
                for (int r = 0; r < 4; ++r) {
                    int b = 4 * q + r;
                    float da = acc[r] * gd_s[b * 68 + 16 * w + c];
                    short hh, ll;
                    cvt1(da, hh, ll);
                    hs[r] = hh; ls[r] = ll;
                }
                *(bf16x4 *)&DAT[(16 * w + c) * 16 + 4 * q] = hs;
                *(bf16x4 *)&DAT[(16 * w + c) * 16 + 8 + 4 * q] = ls;
            }
            __syncthreads();
            // update: W1 -= LR*k^T@da ; W2(T,R) -= LR*h^T@do (both
            // orientations via packed updW — no scalar scatter); vector
            // params spread across waves 1-3 (wave 0 only does updW).
            updW(KT, DAT, W1T, w, c, q);
            updW(HT, DOT, W2T, w, c, q);
            updW(DOT, HT, W2R, w, c, q);
            if (w == 1) {
                bf16x8 dh_ = *(const bf16x8 *)&DAT[lane * 16];
                bf16x8 dl_ = *(const bf16x8 *)&DAT[lane * 16 + 8];
                float db1 = 0.f;
#pragma unroll
                for (int j = 0; j < 8; ++j)
                    db1 += bf2f(dh_[j]) + bf2f(dl_[j]);
                b1_s[lane] -= LR * db1;
            } else if (w == 2) {
                bf16x8 oh_ = *(const bf16x8 *)&DOT[lane * 16];
                bf16x8 ol_ = *(const bf16x8 *)&DOT[lane * 16 + 8];
                float db2 = 0.f;
#pragma unroll
                for (int j = 0; j < 8; ++j)
                    db2 += bf2f(oh_[j]) + bf2f(ol_[j]);
                b2_s[lane] -= LR * db2;
            } else if (w == 3) {
                float dlb = 0.f, dlg = 0.f;
#pragma unroll
                for (int b = 0; b < 8; ++b) {
                    float dzv = o_s[b * 68 + lane];
                    dlb += dzv;
                    dlg += dzv * xh_s[b * 68 + lane];
                }
                lb_s[lane] -= LR * dlb;
                lg_s[lane] -= LR * dlg;
            }
            __syncthreads();
        }

        // ---- final forward with updated params
        f32x4 acc = mm64(Kp, W1T, w, c, q);
        if (q < 2) {
            float bias = b1_s[16 * w + c];
#pragma unroll
            for (int r = 0; r < 4; ++r) {
                float g = gelu_f(acc[r] + bias);
                int row = 4 * q + r;
                short hh, ll;
                cvt1(g, hh, ll);
                Hp[row * 136 + 16 * w + c] = (unsigned short)hh;
                Hp[row * 136 + 64 + 16 * w + c] = (unsigned short)ll;
            }
        }
        __syncthreads();
        acc = mm64(Hp, W2T, w, c, q);
        if (q < 2) {
            float bias = b2_s[16 * w + c];
#pragma unroll
            for (int r = 0; r < 4; ++r)
                o_s[(4 * q + r) * 68 + 16 * w + c] = acc[r] + bias;
        }
        __syncthreads();
        // epilogue: LN(lg,lb) -> LN(ttt_g,ttt_b) -> out = q + z2 ; prefetch t+1
        {
            float2 xv = *(const float2 *)&o_s[bb * 68 + j0];
            float mu = red32(xv.x + xv.y) * (1.f / 64.f);
            float d0 = xv.x - mu, d1 = xv.y - mu;
            float var = red32(d0 * d0 + d1 * d1) * (1.f / 64.f);
            float rs = rsqrtf(var + 1e-5f);
            float z0 = d0 * rs * lg_s[j0] + lb_s[j0];
            float z1 = d1 * rs * lg_s[j0 + 1] + lb_s[j0 + 1];
            float mu2 = red32(z0 + z1) * (1.f / 64.f);
            float e0 = z0 - mu2, e1 = z1 - mu2;
            float var2 = red32(e0 * e0 + e1 * e1) * (1.f / 64.f);
            float rs2 = rsqrtf(var2 + 1e-5f);
            float z20 = e0 * rs2 * tG_s[j0] + tB_s[j0];
            float z21 = e1 * rs2 * tG_s[j0 + 1] + tB_s[j0 + 1];
            int idx = ((bb * Sv + t) * Hv + h) * Dv + j0;
            float2 ov;
            ov.x = pq.x + z20;
            ov.y = pq.y + z21;
            *(float2 *)&out_g[idx] = ov;
            if (t + 1 < Sv) {
                int idx2 = ((bb * Sv + t + 1) * Hv + h) * Dv + j0;
                pk = *(const float2 *)&k_g[idx2];
                pv = *(const float2 *)&v_g[idx2];
                pq = *(const float2 *)&q_g[idx2];
            }
        }
        // no barrier needed here: prologue writes (Kp/KT/TGp) have no readers
        // still in flight (all waves passed the F2-final barrier of token t)
    }
}

// ---------------------------------------------------------------------------
// fp32 GEMM: C[M,N] = A[M,K] @ B[K,N]; mode 1: C = gelu(acc) * gate_ln
// ---------------------------------------------------------------------------
__global__ __launch_bounds__(256) void gemm_f32(
    const float *__restrict__ A, const float *__restrict__ B,
    float *__restrict__ C, const float *__restrict__ gate_ln,
    int M, int N, int K, int mode) {
    __shared__ float As[16][68];
    __shared__ float Bs[16][64];
    const int tid = threadIdx.x;
    const int tx = tid & 15, ty = tid >> 4;
    const int bm = blockIdx.y * 64, bn = blockIdx.x * 64;

    float acc[4][4] = {};
    for (int k0 = 0; k0 < K; k0 += 16) {
        {
            int r = tid >> 2, kk = (tid & 3) * 4;
            float4 av = *(const float4 *)(A + (long)(bm + r) * K + k0 + kk);
            As[kk + 0][r] = av.x;
            As[kk + 1][r] = av.y;
            As[kk + 2][r] = av.z;
            As[kk + 3][r] = av.w;
            int rr = tid >> 4, cc = (tid & 15) * 4;
            float4 bv = *(const float4 *)(B + (long)(k0 + rr) * N + bn + cc);
            *(float4 *)&Bs[rr][cc] = bv;
        }
        __syncthreads();
#pragma unroll
        for (int kk = 0; kk < 16; ++kk) {
            float4 a4 = *(float4 *)&As[kk][ty * 4];
            float4 b4 = *(float4 *)&Bs[kk][tx * 4];
            float a[4] = {a4.x, a4.y, a4.z, a4.w};
            float b[4] = {b4.x, b4.y, b4.z, b4.w};
#pragma unroll
            for (int i = 0; i < 4; ++i)
#pragma unroll
                for (int j = 0; j < 4; ++j) acc[i][j] += a[i] * b[j];
        }
        __syncthreads();
    }
#pragma unroll
    for (int i = 0; i < 4; ++i) {
        int row = bm + ty * 4 + i;
        float4 out;
        float v[4];
#pragma unroll
        for (int j = 0; j < 4; ++j) {
            float val = acc[i][j];
            if (mode == 1) {
                int col = bn + tx * 4 + j;
                val = gelu_f(val) * gate_ln[(long)row * N + col];
            }
            v[j] = val;
        }
        out.x = v[0]; out.y = v[1]; out.z = v[2]; out.w = v[3];
        *(float4 *)(C + (long)row * N + bn + tx * 4) = out;
    }
}

// ---------------------------------------------------------------------------
// Row LayerNorm over 1024 (post-scan, pn_g / pn_b)
// ---------------------------------------------------------------------------
__global__ __launch_bounds__(256) void row_ln(const float *__restrict__ in,
                                              float *__restrict__ out,
                                              const float *__restrict__ g,
                                              const float *__restrict__ b) {
    __shared__ float sred[4], s2red[4];
    const int row = blockIdx.x;
    const int tid = threadIdx.x;
    const float *x = in + (long)row * 1024;
    float4 v = *(const float4 *)(x + tid * 4);
    float s = v.x + v.y + v.z + v.w;
    float s2 = v.x * v.x + v.y * v.y + v.z * v.z + v.w * v.w;
#pragma unroll
    for (int m = 1; m <= 32; m <<= 1) {
        s += __shfl_xor(s, m);
        s2 += __shfl_xor(s2, m);
    }
    if ((tid & 63) == 0) {
        sred[tid >> 6] = s;
        s2red[tid >> 6] = s2;
    }
    __syncthreads();
    float S = sred[0] + sred[1] + sred[2] + sred[3];
    float S2 = s2red[0] + s2red[1] + s2red[2] + s2red[3];
    float mu = S * (1.f / 1024.f);
    float var = S2 * (1.f / 1024.f) - mu * mu;
    float rs = rsqrtf(var + 1e-5f);
    float o[4] = {v.x, v.y, v.z, v.w};
    float4 ov;
    float r[4];
#pragma unroll
    for (int i = 0; i < 4; ++i) {
        int col = tid * 4 + i;
        r[i] = (o[i] - mu) * rs * g[col] + b[col];
    }
    ov.x = r[0]; ov.y = r[1]; ov.z = r[2]; ov.w = r[3];
    *(float4 *)(out + (long)row * 1024 + tid * 4) = ov;
}

// ---------------------------------------------------------------------------
// Launch
// ---------------------------------------------------------------------------
extern "C" void kernel_launch(void *const *d_in, const int *in_sizes, int n_in,
                              void *d_out, int out_size, void *d_ws,
                              size_t ws_size, hipStream_t stream) {
    const float *x = (const float *)d_in[0];
    const float *wq = (const float *)d_in[1];
    const float *wk = (const float *)d_in[2];
    const float *wv = (const float *)d_in[3];
    const float *fw_w1 = (const float *)d_in[4];
    const float *fw_b1 = (const float *)d_in[5];
    const float *fw_w2 = (const float *)d_in[6];
    const float *fw_b2 = (const float *)d_in[7];
    const float *fw_lng = (const float *)d_in[8];
    const float *fw_lnb = (const float *)d_in[9];
    const float *loss_w = (const float *)d_in[10];
    const float *loss_b = (const float *)d_in[11];
    const float *ttt_g = (const float *)d_in[12];
    const float *ttt_b = (const float *)d_in[13];
    const float *wo = (const float *)d_in[14];
    const float *wg = (const float *)d_in[15];
    const float *pn_g = (const float *)d_in[16];
    const float *pn_b = (const float *)d_in[17];

    const long MAT = 2048L * 1024L;
    float *q_ws = (float *)d_ws;
    float *k_ws = q_ws + MAT;
    float *v_ws = k_ws + MAT;
    float *out_ws = v_ws + MAT;
    float *ln_ws = k_ws;       // reuse (k dead after scan)
    float *gated_ws = v_ws;    // reuse (v dead after scan)

    dim3 gg(1024 / 64, 2048 / 64), bt(256);
    hipLaunchKernelGGL(gemm_f32, gg, bt, 0, stream, x, wq, q_ws,
                       (const float *)nullptr, 2048, 1024, 1024, 0);
    hipLaunchKernelGGL(gemm_f32, gg, bt, 0, stream, x, wk, k_ws,
                       (const float *)nullptr, 2048, 1024, 1024, 0);
    hipLaunchKernelGGL(gemm_f32, gg, bt, 0, stream, x, wv, v_ws,
                       (const float *)nullptr, 2048, 1024, 1024, 0);

    (void)hipFuncSetAttribute((const void *)ttt_scan,
                              hipFuncAttributeMaxDynamicSharedMemorySize,
                              LDS_BYTES);
    hipLaunchKernelGGL(ttt_scan, dim3(16), dim3(256), LDS_BYTES, stream,
                       q_ws, k_ws, v_ws, out_ws, fw_w1, fw_b1, fw_w2, fw_b2,
                       fw_lng, fw_lnb, loss_w, loss_b, ttt_g, ttt_b);

    hipLaunchKernelGGL(row_ln, dim3(2048), dim3(256), 0, stream, out_ws, ln_ws,
                       pn_g, pn_b);
    hipLaunchKernelGGL(gemm_f32, gg, bt, 0, stream, x, wg, gated_ws, ln_ws,
                       2048, 1024, 1024, 1);
    hipLaunchKernelGGL(gemm_f32, gg, bt, 0, stream, gated_ws, wo,
                       (float *)d_out, (const float *)nullptr, 2048, 1024,
                       1024, 0);
}

// Round 3
// 4749.042 us; speedup vs baseline: 1.3080x; 1.0747x over previous
//
#include <hip/hip_runtime.h>

// ---------------------------------------------------------------------------
// Problem constants
// ---------------------------------------------------------------------------
#define Bv 8
#define Sv 256
#define Hv 16
#define Dv 64
#define LR 0.1f
#define SCALE (2.0f / 8192.0f)   // dLoss/dpred scale: 2/(B*H*D)

using bf16x8 = __attribute__((ext_vector_type(8))) short;
using bf16x4 = __attribute__((ext_vector_type(4))) short;
using f32x4  = __attribute__((ext_vector_type(4))) float;
#define MFMA16(A, B, C) __builtin_amdgcn_mfma_f32_16x16x32_bf16(A, B, C, 0, 0, 0)

// ---------------------------------------------------------------------------
// LDS layout (ushort units for bf16 planes, float units for fp32 areas)
// Weight/row planes: pitch 136 ushort = 272 B (hi[64] | lo[64] | pad[8]).
// T arrays: pitch 16 ushort = 32 B (hi[8] | lo[8]).
// ---------------------------------------------------------------------------
constexpr int U_W1T = 0;          // [f][d] planes, 64x136
constexpr int U_W2T = 8704;      // [d][f]
constexpr int U_W2R = 17408;     // [f][d]
constexpr int U_G   = 26112;     // [d][d']  (symmetric, static)
constexpr int U_LwR = 34816;     // [d][e]   (static)
constexpr int U_K   = 43520;     // [b pad16][d] 16x136
constexpr int U_H   = 45696;     // [b][f]
constexpr int U_Z   = 47872;     // [b][d]
constexpr int U_TG  = 50048;     // [b pad16][e] target planes
constexpr int U_DO  = 52224;     // [b][d]
constexpr int U_KT  = 54400;     // [d][b] 64x16
constexpr int U_HT  = 55424;     // [f][b]
constexpr int U_DOT = 56448;     // [d][b]
constexpr int U_DAT = 57472;     // [f][b]
constexpr int F_BASE = 29248;    // = 58496/2
constexpr int F_O   = F_BASE;        // o / dz shared, [8][68]
constexpr int F_XH  = F_BASE + 544;
constexpr int F_GD  = F_XH + 544;
constexpr int F_TGL = F_GD + 544;    // tgl - c1, [8][68]
constexpr int F_B1  = F_TGL + 544;
constexpr int F_B2  = F_B1 + 64;
constexpr int F_LG  = F_B2 + 64;
constexpr int F_LB  = F_LG + 64;
constexpr int F_C1  = F_LB + 64;     // Lb @ Lw^T (static)
constexpr int F_TGm = F_C1 + 64;
constexpr int F_TBm = F_TGm + 64;
constexpr int F_RSTD = F_TBm + 64;
constexpr int LDS_BYTES = (F_RSTD + 8) * 4;   // 127520 B

// ---------------------------------------------------------------------------
// Helpers
// ---------------------------------------------------------------------------
__device__ __forceinline__ short bf_rn(float v) {
    unsigned u = __float_as_uint(v);
    unsigned r = u + 0x7fffu + ((u >> 16) & 1u);   // round-to-nearest-even
    return (short)(r >> 16);
}
__device__ __forceinline__ void cvt1(float v, short &hi, short &lo) {
    hi = bf_rn(v);
    float hf = __uint_as_float(((unsigned)(unsigned short)hi) << 16);
    lo = bf_rn(v - hf);
}
__device__ __forceinline__ float bf2f(short u) {
    return __uint_as_float(((unsigned)(unsigned short)u) << 16);
}
// Packed bf16 pair conversion: 1 instruction converts 2 floats (RTNE).
__device__ __forceinline__ unsigned cvtpk(float a, float b) {
    unsigned r;
    asm("v_cvt_pk_bf16_f32 %0, %1, %2" : "=v"(r) : "v"(a), "v"(b));
    return r;                      // lo16 = bf16(a), hi16 = bf16(b)
}
// hi/lo split of a float pair: hw = packed hi-bf16s, lw = packed lo-bf16s.
__device__ __forceinline__ void cvt2(float a, float b, unsigned &hw,
                                     unsigned &lw) {
    hw = cvtpk(a, b);
    float ra = a - __uint_as_float(hw << 16);
    float rb = b - __uint_as_float(hw & 0xffff0000u);
    lw = cvtpk(ra, rb);
}
// DPP-based 32-lane sum: 4 VALU-speed DPP adds + 1 cross-row swizzle.
template <int CTRL>
__device__ __forceinline__ float dpp_add(float v) {
    int s = __builtin_amdgcn_update_dpp(0, __float_as_int(v), CTRL, 0xF, 0xF,
                                        true);
    return v + __int_as_float(s);
}
__device__ __forceinline__ float red32(float v) {
    v = dpp_add<0xB1>(v);    // quad_perm [1,0,3,2]  (xor 1)
    v = dpp_add<0x4E>(v);    // quad_perm [2,3,0,1]  (xor 2)
    v = dpp_add<0x124>(v);   // row_ror:4
    v = dpp_add<0x128>(v);   // row_ror:8
    v += __shfl_xor(v, 16);  // merge the two 16-rows of the 32-group
    return v;
}
__device__ __forceinline__ float fast_tanh(float u) {
    u = fminf(fmaxf(u, -10.f), 10.f);
    float e = __expf(2.0f * u);
    return (e - 1.0f) / (e + 1.0f);
}
__device__ __forceinline__ void gelu_both(float x, float &g, float &dg) {
    const float C0 = 0.7978845608028654f, A0 = 0.044715f;
    float x2 = x * x;
    float u = C0 * x * (1.0f + A0 * x2);
    float t = fast_tanh(u);
    g = 0.5f * x * (1.0f + t);
    float du = C0 * (1.0f + 3.0f * A0 * x2);
    dg = 0.5f * (1.0f + t) + 0.5f * x * (1.0f - t * t) * du;
}
__device__ __forceinline__ float gelu_f(float x) {
    const float C0 = 0.7978845608028654f, A0 = 0.044715f;
    float u = C0 * x * (1.0f + A0 * x * x);
    return 0.5f * x * (1.0f + fast_tanh(u));
}

// C[16x16 tile w] = A(16x64, row planes) @ B(64x64 via n-major planes)
__device__ __forceinline__ f32x4 mm64(const unsigned short *Ap,
                                      const unsigned short *Bp,
                                      int w, int c, int q) {
    const unsigned short *ar = Ap + c * 136 + 8 * q;
    const unsigned short *br = Bp + (16 * w + c) * 136 + 8 * q;
    bf16x8 ah0 = *(const bf16x8 *)(ar);
    bf16x8 al0 = *(const bf16x8 *)(ar + 64);
    bf16x8 bh0 = *(const bf16x8 *)(br);
    bf16x8 bl0 = *(const bf16x8 *)(br + 64);
    bf16x8 ah1 = *(const bf16x8 *)(ar + 32);
    bf16x8 al1 = *(const bf16x8 *)(ar + 96);
    bf16x8 bh1 = *(const bf16x8 *)(br + 32);
    bf16x8 bl1 = *(const bf16x8 *)(br + 96);
    f32x4 x0 = {0.f, 0.f, 0.f, 0.f}, x1 = {0.f, 0.f, 0.f, 0.f};
    x0 = MFMA16(ah0, bh0, x0); x1 = MFMA16(ah1, bh1, x1);
    x0 = MFMA16(al0, bh0, x0); x1 = MFMA16(al1, bh1, x1);
    x0 = MFMA16(ah0, bl0, x0); x1 = MFMA16(ah1, bl1, x1);
    x0 = MFMA16(al0, bl0, x0); x1 = MFMA16(al1, bl1, x1);
    return x0 + x1;
}

// W(tile col n=16w+c) -= LR * X^T@Y ; X,Y given as T-arrays [64][b:8|8] bf16.
// Packed-K: one MFMA per 16-row block computes hh+lh+hl via K-chunks.
// NOTE (fused-phase contract): B-operand (YT) reads only rows 16w+c; W RMW
// touches only rows 16w+c -> wave-exclusive, safe without a barrier when the
// producing phase wrote YT cols 16w+c in the same wave.
__device__ __forceinline__ void updW(const unsigned short *XT,
                                     const unsigned short *YT,
                                     unsigned short *WT,
                                     int w, int c, int q) {
    bf16x8 zf;
#pragma unroll
    for (int j = 0; j < 8; ++j) zf[j] = 0;
    bf16x8 b = zf;
    if (q < 2)
        b = *(const bf16x8 *)&YT[(16 * w + c) * 16];
    else if (q == 2)
        b = *(const bf16x8 *)&YT[(16 * w + c) * 16 + 8];
    f32x4 g[4];
#pragma unroll
    for (int mt = 0; mt < 4; ++mt) {
        bf16x8 a = *(const bf16x8 *)&XT[(16 * mt + c) * 16 + (q & 1) * 8];
        f32x4 z = {0.f, 0.f, 0.f, 0.f};
        g[mt] = MFMA16(a, b, z);
    }
#pragma unroll
    for (int mt = 0; mt < 4; ++mt) {
        unsigned short *ph = &WT[(16 * w + c) * 136 + 16 * mt + 4 * q];
        unsigned short *pl = ph + 64;
        uint2 oh = *(uint2 *)ph, ol = *(uint2 *)pl;
        float v0 = __uint_as_float(oh.x << 16) +
                   __uint_as_float(ol.x << 16) - LR * g[mt][0];
        float v1 = __uint_as_float(oh.x & 0xffff0000u) +
                   __uint_as_float(ol.x & 0xffff0000u) - LR * g[mt][1];
        float v2 = __uint_as_float(oh.y << 16) +
                   __uint_as_float(ol.y << 16) - LR * g[mt][2];
        float v3 = __uint_as_float(oh.y & 0xffff0000u) +
                   __uint_as_float(ol.y & 0xffff0000u) - LR * g[mt][3];
        unsigned nh0, nl0, nh1, nl1;
        cvt2(v0, v1, nh0, nl0);
        cvt2(v2, v3, nh1, nl1);
        uint2 nh, nl;
        nh.x = nh0; nh.y = nh1;
        nl.x = nl0; nl.y = nl1;
        *(uint2 *)ph = nh;
        *(uint2 *)pl = nl;
    }
}

// ---------------------------------------------------------------------------
// TTT scan kernel: one block (256 thr = 4 waves) per head
// Phase plan per step (6 barriers): F1 | F2 | LNf | B1' | LNb | B2+upd
// Token tail: F1fin | F2fin(+stage t+1) | epilogue (no barrier)
// ---------------------------------------------------------------------------
__global__ __launch_bounds__(256) void ttt_scan(
    const float *__restrict__ q_g, const float *__restrict__ k_g,
    const float *__restrict__ v_g, float *__restrict__ out_g,
    const float *__restrict__ fw_w1, const float *__restrict__ fw_b1,
    const float *__restrict__ fw_w2, const float *__restrict__ fw_b2,
    const float *__restrict__ fw_lng, const float *__restrict__ fw_lnb,
    const float *__restrict__ loss_w, const float *__restrict__ loss_bv,
    const float *__restrict__ ttt_gv, const float *__restrict__ ttt_bv) {
    extern __shared__ char smem[];
    unsigned short *us = (unsigned short *)smem;
    float *fs = (float *)smem;

    unsigned short *W1T = us + U_W1T, *W2T = us + U_W2T, *W2R = us + U_W2R;
    unsigned short *Gp = us + U_G, *LwR = us + U_LwR;
    unsigned short *Kp = us + U_K, *Hp = us + U_H, *Zp = us + U_Z;
    unsigned short *TGp = us + U_TG, *DOp = us + U_DO;
    unsigned short *KT = us + U_KT, *HT = us + U_HT;
    unsigned short *DOT = us + U_DOT, *DAT = us + U_DAT;
    float *o_s = fs + F_O, *xh_s = fs + F_XH, *gd_s = fs + F_GD;
    float *TGL = fs + F_TGL;
    float *b1_s = fs + F_B1, *b2_s = fs + F_B2, *lg_s = fs + F_LG;
    float *lb_s = fs + F_LB, *c1_s = fs + F_C1;
    float *tG_s = fs + F_TGm, *tB_s = fs + F_TBm, *rstd_s = fs + F_RSTD;

    const int h = blockIdx.x, tid = threadIdx.x;
    const int w = tid >> 6, lane = tid & 63, c = lane & 15, q = lane >> 4;
    const int bb = tid >> 5, j0 = (tid & 31) * 2;

    // ---- init: split weights into bf16 hi/lo planes
    for (int i = tid; i < 4096; i += 256) {
        int r = i >> 6, cc = i & 63;
        short hi, lo;
        cvt1(fw_w1[h * 4096 + i], hi, lo);           // [d=r][f=cc]
        W1T[cc * 136 + r] = (unsigned short)hi;
        W1T[cc * 136 + 64 + r] = (unsigned short)lo;
        cvt1(fw_w2[h * 4096 + i], hi, lo);           // [f=r][d=cc]
        W2T[cc * 136 + r] = (unsigned short)hi;
        W2T[cc * 136 + 64 + r] = (unsigned short)lo;
        W2R[r * 136 + cc] = (unsigned short)hi;
        W2R[r * 136 + 64 + cc] = (unsigned short)lo;
        cvt1(loss_w[i], hi, lo);                     // [d=r][e=cc]
        LwR[r * 136 + cc] = (unsigned short)hi;
        LwR[r * 136 + 64 + cc] = (unsigned short)lo;
    }
    // zero pad rows 8..15 of the 5 activation row-plane arrays
    for (int i = tid; i < 5 * 8 * 128; i += 256) {
        int a = i / 128, u = i % 128;
        int arr = a >> 3, row = 8 + (a & 7);
        unsigned short *base = (arr == 0) ? Kp : (arr == 1) ? Hp
                              : (arr == 2) ? Zp : (arr == 3) ? TGp : DOp;
        base[row * 136 + u] = 0;
    }
    __syncthreads();
    // G = Lw @ Lw^T (static; fuses F3+B1 into one phase per step)
#pragma unroll 1
    for (int mt = 0; mt < 4; ++mt) {
        f32x4 g = mm64(LwR + 16 * 136 * mt, LwR, w, c, q);
#pragma unroll
        for (int r = 0; r < 4; ++r) {
            short hi, lo;
            cvt1(g[r], hi, lo);
            int dr = 16 * mt + 4 * q + r, dc = 16 * w + c;
            Gp[dr * 136 + dc] = (unsigned short)hi;
            Gp[dr * 136 + 64 + dc] = (unsigned short)lo;
        }
    }
    if (tid < 64) {
        b1_s[tid] = fw_b1[h * 64 + tid];
        b2_s[tid] = fw_b2[h * 64 + tid];
        lg_s[tid] = fw_lng[h * 64 + tid];
        lb_s[tid] = fw_lnb[h * 64 + tid];
        tG_s[tid] = ttt_gv[h * 64 + tid];
        tB_s[tid] = ttt_bv[h * 64 + tid];
        float c1 = 0.f;                      // c1[d] = sum_e Lb[e]*Lw[d,e]
        for (int e = 0; e < 64; ++e) c1 += loss_bv[e] * loss_w[tid * 64 + e];
        c1_s[tid] = c1;
    }

    // ---- stage token 0 (Kp/KT/TGp) and hold q(0) in registers
    float2 pk, pv, pq, q_cur;
    {
        int idx = ((bb * Sv + 0) * Hv + h) * Dv + j0;
        float2 k0 = *(const float2 *)&k_g[idx];
        float2 v0 = *(const float2 *)&v_g[idx];
        q_cur = *(const float2 *)&q_g[idx];
        unsigned khw, klw;
        cvt2(k0.x, k0.y, khw, klw);
        *(unsigned *)&Kp[bb * 136 + j0] = khw;
        *(unsigned *)&Kp[bb * 136 + 64 + j0] = klw;
        KT[j0 * 16 + bb] = (unsigned short)khw;
        KT[j0 * 16 + 8 + bb] = (unsigned short)klw;
        KT[(j0 + 1) * 16 + bb] = (unsigned short)(khw >> 16);
        KT[(j0 + 1) * 16 + 8 + bb] = (unsigned short)(klw >> 16);
        unsigned thw, tlw;
        cvt2(v0.x - k0.x, v0.y - k0.y, thw, tlw);
        *(unsigned *)&TGp[bb * 136 + j0] = thw;
        *(unsigned *)&TGp[bb * 136 + 64 + j0] = tlw;
    }
    __syncthreads();

#pragma unroll 1
    for (int t = 0; t < Sv; ++t) {
        // issue prefetch for token t+1 (consumed at F2fin staging / epilogue)
        if (t + 1 < Sv) {
            int idx2 = ((bb * Sv + t + 1) * Hv + h) * Dv + j0;
            pk = *(const float2 *)&k_g[idx2];
            pv = *(const float2 *)&v_g[idx2];
            pq = *(const float2 *)&q_g[idx2];
        }

#pragma unroll 1
        for (int step = 0; step < 4; ++step) {
            // F1: h = gelu(k@W1 + b1)   [+ tgl = tg@Lw^T once per token]
            f32x4 acc = mm64(Kp, W1T, w, c, q);
            if (step == 0) {
                f32x4 a2 = mm64(TGp, LwR, w, c, q);
                if (q < 2) {
                    int col = 16 * w + c;
#pragma unroll
                    for (int r = 0; r < 4; ++r)
                        TGL[(4 * q + r) * 68 + col] = a2[r] - c1_s[col];
                }
            }
            if (q < 2) {
                int col = 16 * w + c;
                float bias = b1_s[col];
                float gv[4];
#pragma unroll
                for (int r = 0; r < 4; ++r) {
                    float g, dg;
                    gelu_both(acc[r] + bias, g, dg);
                    gv[r] = g;
                    gd_s[(4 * q + r) * 68 + col] = dg;
                }
                unsigned h01, l01, h23, l23;
                cvt2(gv[0], gv[1], h01, l01);
                cvt2(gv[2], gv[3], h23, l23);
                Hp[(4 * q + 0) * 136 + col] = (unsigned short)h01;
                Hp[(4 * q + 1) * 136 + col] = (unsigned short)(h01 >> 16);
                Hp[(4 * q + 2) * 136 + col] = (unsigned short)h23;
                Hp[(4 * q + 3) * 136 + col] = (unsigned short)(h23 >> 16);
                Hp[(4 * q + 0) * 136 + 64 + col] = (unsigned short)l01;
                Hp[(4 * q + 1) * 136 + 64 + col] = (unsigned short)(l01 >> 16);
                Hp[(4 * q + 2) * 136 + 64 + col] = (unsigned short)l23;
                Hp[(4 * q + 3) * 136 + 64 + col] = (unsigned short)(l23 >> 16);
                uint2 hh, hl;
                hh.x = h01; hh.y = h23;
                hl.x = l01; hl.y = l23;
                *(uint2 *)&HT[col * 16 + 4 * q] = hh;
                *(uint2 *)&HT[col * 16 + 8 + 4 * q] = hl;
            }
            __syncthreads();
            // F2: o = h@W2 + b2
            acc = mm64(Hp, W2T, w, c, q);
            if (q < 2) {
                float bias = b2_s[16 * w + c];
#pragma unroll
                for (int r = 0; r < 4; ++r)
                    o_s[(4 * q + r) * 68 + 16 * w + c] = acc[r] + bias;
            }
            __syncthreads();
            // LN fwd (thread-mapped); xh kept in regs for LNb
            float xh0_r, xh1_r;
            {
                float2 xv = *(const float2 *)&o_s[bb * 68 + j0];
                float mu = red32(xv.x + xv.y) * (1.f / 64.f);
                float d0 = xv.x - mu, d1 = xv.y - mu;
                float var = red32(d0 * d0 + d1 * d1) * (1.f / 64.f);
                float rs = rsqrtf(var + 1e-5f);
                float xh0 = d0 * rs, xh1 = d1 * rs;
                float2 xw; xw.x = xh0; xw.y = xh1;
                *(float2 *)&xh_s[bb * 68 + j0] = xw;
                float z0 = xh0 * lg_s[j0] + lb_s[j0];
                float z1 = xh1 * lg_s[j0 + 1] + lb_s[j0 + 1];
                unsigned zh, zl;
                cvt2(z0, z1, zh, zl);
                *(unsigned *)&Zp[bb * 136 + j0] = zh;
                *(unsigned *)&Zp[bb * 136 + 64 + j0] = zl;
                if ((tid & 31) == 0) rstd_s[bb] = rs;
                xh0_r = xh0; xh1_r = xh1;
            }
            __syncthreads();
            // B1' (fused F3+B1): dz = SCALE * (z@G - (tgl - c1))
            acc = mm64(Zp, Gp, w, c, q);
            if (q < 2) {
                int col = 16 * w + c;
#pragma unroll
                for (int r = 0; r < 4; ++r) {
                    int row = 4 * q + r;
                    o_s[row * 68 + col] =
                        (acc[r] - TGL[row * 68 + col]) * SCALE;
                }
            }
            __syncthreads();
            // LN bwd (thread-mapped) -> do planes + doT
            {
                float2 dzv = *(const float2 *)&o_s[bb * 68 + j0];
                float dxh0 = dzv.x * lg_s[j0], dxh1 = dzv.y * lg_s[j0 + 1];
                float S1 = red32(dxh0 + dxh1) * (1.f / 64.f);
                float S2 = red32(dxh0 * xh0_r + dxh1 * xh1_r) * (1.f / 64.f);
                float rs = rstd_s[bb];
                float do0 = rs * (dxh0 - S1 - xh0_r * S2);
                float do1 = rs * (dxh1 - S1 - xh1_r * S2);
                unsigned dh, dl;
                cvt2(do0, do1, dh, dl);
                *(unsigned *)&DOp[bb * 136 + j0] = dh;
                *(unsigned *)&DOp[bb * 136 + 64 + j0] = dl;
                DOT[j0 * 16 + bb] = (unsigned short)dh;
                DOT[j0 * 16 + 8 + bb] = (unsigned short)dl;
                DOT[(j0 + 1) * 16 + bb] = (unsigned short)(dh >> 16);
                DOT[(j0 + 1) * 16 + 8 + bb] = (unsigned short)(dl >> 16);
            }
            __syncthreads();
            // B2+upd (fused, single phase): dh = do@W2^T ; da = dh*gelu' ->
            // DAT (wave-local cols); then all three weight updates + vector
            // params. mm64's W2R read precedes the same wave's W2R RMW in
            // program order; DAT write->read is same-wave (DS in-order).
            acc = mm64(DOp, W2R, w, c, q);
            {
                float b1sum = 0.f;
                if (q < 2) {
                    int col = 16 * w + c;
                    float da0 = acc[0] * gd_s[(4 * q + 0) * 68 + col];
                    float da1 = acc[1] * gd_s[(4 * q + 1) * 68 + col];
                    float da2 = acc[2] * gd_s[(4 * q + 2) * 68 + col];
                    float da3 = acc[3] * gd_s[(4 * q + 3) * 68 + col];
                    b1sum = da0 + da1 + da2 + da3;
                    unsigned h01, l01, h23, l23;
                    cvt2(da0, da1, h01, l01);
                    cvt2(da2, da3, h23, l23);
                    uint2 th, tl;
                    th.x = h01; th.y = h23;
                    tl.x = l01; tl.y = l23;
                    *(uint2 *)&DAT[col * 16 + 4 * q] = th;
                    *(uint2 *)&DAT[col * 16 + 8 + 4 * q] = tl;
                }
                b1sum += __shfl_xor(b1sum, 16);
                updW(KT, DAT, W1T, w, c, q);
                updW(HT, DOT, W2T, w, c, q);
                updW(DOT, HT, W2R, w, c, q);
                if (q == 0) b1_s[16 * w + c] -= LR * b1sum;
                if (w == 2) {
                    bf16x8 oh_ = *(const bf16x8 *)&DOT[lane * 16];
                    bf16x8 ol_ = *(const bf16x8 *)&DOT[lane * 16 + 8];
                    float db2 = 0.f;
#pragma unroll
                    for (int j = 0; j < 8; ++j)
                        db2 += bf2f(oh_[j]) + bf2f(ol_[j]);
                    b2_s[lane] -= LR * db2;
                } else if (w == 3) {
                    float dlb = 0.f, dlg = 0.f;
#pragma unroll
                    for (int b = 0; b < 8; ++b) {
                        float dzv = o_s[b * 68 + lane];
                        dlb += dzv;
                        dlg += dzv * xh_s[b * 68 + lane];
                    }
                    lb_s[lane] -= LR * dlb;
                    lg_s[lane] -= LR * dlg;
                }
            }
            __syncthreads();
        }

        // ---- final forward with updated params
        f32x4 acc = mm64(Kp, W1T, w, c, q);
        if (q < 2) {
            int col = 16 * w + c;
            float bias = b1_s[col];
            float gv[4];
#pragma unroll
            for (int r = 0; r < 4; ++r) gv[r] = gelu_f(acc[r] + bias);
            unsigned h01, l01, h23, l23;
            cvt2(gv[0], gv[1], h01, l01);
            cvt2(gv[2], gv[3], h23, l23);
            Hp[(4 * q + 0) * 136 + col] = (unsigned short)h01;
            Hp[(4 * q + 1) * 136 + col] = (unsigned short)(h01 >> 16);
            Hp[(4 * q + 2) * 136 + col] = (unsigned short)h23;
            Hp[(4 * q + 3) * 136 + col] = (unsigned short)(h23 >> 16);
            Hp[(4 * q + 0) * 136 + 64 + col] = (unsigned short)l01;
            Hp[(4 * q + 1) * 136 + 64 + col] = (unsigned short)(l01 >> 16);
            Hp[(4 * q + 2) * 136 + 64 + col] = (unsigned short)l23;
            Hp[(4 * q + 3) * 136 + 64 + col] = (unsigned short)(l23 >> 16);
        }
        __syncthreads();
        // F2fin: o = h@W2 + b2 ; also stage token t+1 (Kp/KT/TGp) — Kp's
        // last reader (F1fin) is behind the previous barrier.
        acc = mm64(Hp, W2T, w, c, q);
        if (q < 2) {
            float bias = b2_s[16 * w + c];
#pragma unroll
            for (int r = 0; r < 4; ++r)
                o_s[(4 * q + r) * 68 + 16 * w + c] = acc[r] + bias;
        }
        if (t + 1 < Sv) {
            unsigned khw, klw;
            cvt2(pk.x, pk.y, khw, klw);
            *(unsigned *)&Kp[bb * 136 + j0] = khw;
            *(unsigned *)&Kp[bb * 136 + 64 + j0] = klw;
            KT[j0 * 16 + bb] = (unsigned short)khw;
            KT[j0 * 16 + 8 + bb] = (unsigned short)klw;
            KT[(j0 + 1) * 16 + bb] = (unsigned short)(khw >> 16);
            KT[(j0 + 1) * 16 + 8 + bb] = (unsigned short)(klw >> 16);
            unsigned thw, tlw;
            cvt2(pv.x - pk.x, pv.y - pk.y, thw, tlw);
            *(unsigned *)&TGp[bb * 136 + j0] = thw;
            *(unsigned *)&TGp[bb * 136 + 64 + j0] = tlw;
        }
        __syncthreads();
        // epilogue: LN(lg,lb) -> LN(ttt_g,ttt_b) -> out = q + z2
        // (no trailing barrier: next F1's end-barrier orders o_s reuse)
        {
            float2 xv = *(const float2 *)&o_s[bb * 68 + j0];
            float mu = red32(xv.x + xv.y) * (1.f / 64.f);
            float d0 = xv.x - mu, d1 = xv.y - mu;
            float var = red32(d0 * d0 + d1 * d1) * (1.f / 64.f);
            float rs = rsqrtf(var + 1e-5f);
            float z0 = d0 * rs * lg_s[j0] + lb_s[j0];
            float z1 = d1 * rs * lg_s[j0 + 1] + lb_s[j0 + 1];
            float mu2 = red32(z0 + z1) * (1.f / 64.f);
            float e0 = z0 - mu2, e1 = z1 - mu2;
            float var2 = red32(e0 * e0 + e1 * e1) * (1.f / 64.f);
            float rs2 = rsqrtf(var2 + 1e-5f);
            float z20 = e0 * rs2 * tG_s[j0] + tB_s[j0];
            float z21 = e1 * rs2 * tG_s[j0 + 1] + tB_s[j0 + 1];
            int idx = ((bb * Sv + t) * Hv + h) * Dv + j0;
            float2 ov;
            ov.x = q_cur.x + z20;
            ov.y = q_cur.y + z21;
            *(float2 *)&out_g[idx] = ov;
            q_cur = pq;
        }
    }
}

// ---------------------------------------------------------------------------
// fp32 GEMM: C[M,N] = A[M,K] @ B[K,N]; mode 1: C = gelu(acc) * gate_ln
// ---------------------------------------------------------------------------
__global__ __launch_bounds__(256) void gemm_f32(
    const float *__restrict__ A, const float *__restrict__ B,
    float *__restrict__ C, const float *__restrict__ gate_ln,
    int M, int N, int K, int mode) {
    __shared__ float As[16][68];
    __shared__ float Bs[16][64];
    const int tid = threadIdx.x;
    const int tx = tid & 15, ty = tid >> 4;
    const int bm = blockIdx.y * 64, bn = blockIdx.x * 64;

    float acc[4][4] = {};
    for (int k0 = 0; k0 < K; k0 += 16) {
        {
            int r = tid >> 2, kk = (tid & 3) * 4;
            float4 av = *(const float4 *)(A + (long)(bm + r) * K + k0 + kk);
            As[kk + 0][r] = av.x;
            As[kk + 1][r] = av.y;
            As[kk + 2][r] = av.z;
            As[kk + 3][r] = av.w;
            int rr = tid >> 4, cc = (tid & 15) * 4;
            float4 bv = *(const float4 *)(B + (long)(k0 + rr) * N + bn + cc);
            *(float4 *)&Bs[rr][cc] = bv;
        }
        __syncthreads();
#pragma unroll
        for (int kk = 0; kk < 16; ++kk) {
            float4 a4 = *(float4 *)&As[kk][ty * 4];
            float4 b4 = *(float4 *)&Bs[kk][tx * 4];
            float a[4] = {a4.x, a4.y, a4.z, a4.w};
            float b[4] = {b4.x, b4.y, b4.z, b4.w};
#pragma unroll
            for (int i = 0; i < 4; ++i)
#pragma unroll
                for (int j = 0; j < 4; ++j) acc[i][j] += a[i] * b[j];
        }
        __syncthreads();
    }
#pragma unroll
    for (int i = 0; i < 4; ++i) {
        int row = bm + ty * 4 + i;
        float4 out;
        float v[4];
#pragma unroll
        for (int j = 0; j < 4; ++j) {
            float val = acc[i][j];
            if (mode == 1) {
                int col = bn + tx * 4 + j;
                val = gelu_f(val) * gate_ln[(long)row * N + col];
            }
            v[j] = val;
        }
        out.x = v[0]; out.y = v[1]; out.z = v[2]; out.w = v[3];
        *(float4 *)(C + (long)row * N + bn + tx * 4) = out;
    }
}

// ---------------------------------------------------------------------------
// Row LayerNorm over 1024 (post-scan, pn_g / pn_b)
// ---------------------------------------------------------------------------
__global__ __launch_bounds__(256) void row_ln(const float *__restrict__ in,
                                              float *__restrict__ out,
                                              const float *__restrict__ g,
                                              const float *__restrict__ b) {
    __shared__ float sred[4], s2red[4];
    const int row = blockIdx.x;
    const int tid = threadIdx.x;
    const float *x = in + (long)row * 1024;
    float4 v = *(const float4 *)(x + tid * 4);
    float s = v.x + v.y + v.z + v.w;
    float s2 = v.x * v.x + v.y * v.y + v.z * v.z + v.w * v.w;
#pragma unroll
    for (int m = 1; m <= 32; m <<= 1) {
        s += __shfl_xor(s, m);
        s2 += __shfl_xor(s2, m);
    }
    if ((tid & 63) == 0) {
        sred[tid >> 6] = s;
        s2red[tid >> 6] = s2;
    }
    __syncthreads();
    float S = sred[0] + sred[1] + sred[2] + sred[3];
    float S2 = s2red[0] + s2red[1] + s2red[2] + s2red[3];
    float mu = S * (1.f / 1024.f);
    float var = S2 * (1.f / 1024.f) - mu * mu;
    float rs = rsqrtf(var + 1e-5f);
    float o[4] = {v.x, v.y, v.z, v.w};
    float4 ov;
    float r[4];
#pragma unroll
    for (int i = 0; i < 4; ++i) {
        int col = tid * 4 + i;
        r[i] = (o[i] - mu) * rs * g[col] + b[col];
    }
    ov.x = r[0]; ov.y = r[1]; ov.z = r[2]; ov.w = r[3];
    *(float4 *)(out + (long)row * 1024 + tid * 4) = ov;
}

// ---------------------------------------------------------------------------
// Launch
// ---------------------------------------------------------------------------
extern "C" void kernel_launch(void *const *d_in, const int *in_sizes, int n_in,
                              void *d_out, int out_size, void *d_ws,
                              size_t ws_size, hipStream_t stream) {
    const float *x = (const float *)d_in[0];
    const float *wq = (const float *)d_in[1];
    const float *wk = (const float *)d_in[2];
    const float *wv = (const float *)d_in[3];
    const float *fw_w1 = (const float *)d_in[4];
    const float *fw_b1 = (const float *)d_in[5];
    const float *fw_w2 = (const float *)d_in[6];
    const float *fw_b2 = (const float *)d_in[7];
    const float *fw_lng = (const float *)d_in[8];
    const float *fw_lnb = (const float *)d_in[9];
    const float *loss_w = (const float *)d_in[10];
    const float *loss_b = (const float *)d_in[11];
    const float *ttt_g = (const float *)d_in[12];
    const float *ttt_b = (const float *)d_in[13];
    const float *wo = (const float *)d_in[14];
    const float *wg = (const float *)d_in[15];
    const float *pn_g = (const float *)d_in[16];
    const float *pn_b = (const float *)d_in[17];

    const long MAT = 2048L * 1024L;
    float *q_ws = (float *)d_ws;
    float *k_ws = q_ws + MAT;
    float *v_ws = k_ws + MAT;
    float *out_ws = v_ws + MAT;
    float *ln_ws = k_ws;       // reuse (k dead after scan)
    float *gated_ws = v_ws;    // reuse (v dead after scan)

    dim3 gg(1024 / 64, 2048 / 64), bt(256);
    hipLaunchKernelGGL(gemm_f32, gg, bt, 0, stream, x, wq, q_ws,
                       (const float *)nullptr, 2048, 1024, 1024, 0);
    hipLaunchKernelGGL(gemm_f32, gg, bt, 0, stream, x, wk, k_ws,
                       (const float *)nullptr, 2048, 1024, 1024, 0);
    hipLaunchKernelGGL(gemm_f32, gg, bt, 0, stream, x, wv, v_ws,
                       (const float *)nullptr, 2048, 1024, 1024, 0);

    (void)hipFuncSetAttribute((const void *)ttt_scan,
                              hipFuncAttributeMaxDynamicSharedMemorySize,
                              LDS_BYTES);
    hipLaunchKernelGGL(ttt_scan, dim3(16), dim3(256), LDS_BYTES, stream,
                       q_ws, k_ws, v_ws, out_ws, fw_w1, fw_b1, fw_w2, fw_b2,
                       fw_lng, fw_lnb, loss_w, loss_b, ttt_g, ttt_b);

    hipLaunchKernelGGL(row_ln, dim3(2048), dim3(256), 0, stream, out_ws, ln_ws,
                       pn_g, pn_b);
    hipLaunchKernelGGL(gemm_f32, gg, bt, 0, stream, x, wg, gated_ws, ln_ws,
                       2048, 1024, 1024, 1);
    hipLaunchKernelGGL(gemm_f32, gg, bt, 0, stream, gated_ws, wo,
                       (float *)d_out, (const float *)nullptr, 2048, 1024,
                       1024, 0);
}

// Round 4
// 4570.440 us; speedup vs baseline: 1.3592x; 1.0391x over previous
//
#include <hip/hip_runtime.h>

// ---------------------------------------------------------------------------
// Problem constants
// ---------------------------------------------------------------------------
#define Bv 8
#define Sv 256
#define Hv 16
#define Dv 64
#define LR 0.1f
#define SCALE (2.0f / 8192.0f)   // dLoss/dpred scale: 2/(B*H*D)

using bf16x8 = __attribute__((ext_vector_type(8))) short;
using bf16x4 = __attribute__((ext_vector_type(4))) short;
using f32x4  = __attribute__((ext_vector_type(4))) float;
#define MFMA16(A, B, C) __builtin_amdgcn_mfma_f32_16x16x32_bf16(A, B, C, 0, 0, 0)

// ---------------------------------------------------------------------------
// LDS layout (ushort units for bf16 planes, float units for fp32 areas)
// Weight/row planes: pitch 136 ushort = 272 B (hi[64] | lo[64] | pad[8]).
// T arrays: pitch 16 ushort = 32 B (hi[8] | lo[8]).
// ---------------------------------------------------------------------------
constexpr int U_W1T = 0;          // [f][d] planes, 64x136
constexpr int U_W2T = 8704;      // [d][f]
constexpr int U_W2R = 17408;     // [f][d]
constexpr int U_G   = 26112;     // [d][d']  (symmetric, static)
constexpr int U_LwR = 34816;     // [d][e]   (static)
constexpr int U_K   = 43520;     // [b pad16][d] 16x136
constexpr int U_H   = 45696;     // [b][f]
constexpr int U_Z   = 47872;     // [b][d]
constexpr int U_TG  = 50048;     // [b pad16][e] target planes
constexpr int U_DO  = 52224;     // [b][d]
constexpr int U_KT  = 54400;     // [d][b] 64x16
constexpr int U_HT  = 55424;     // [f][b]  (buffer 0)
constexpr int U_DOT = 56448;     // [d][b]
constexpr int U_DAT = 57472;     // [f][b]
constexpr int F_BASE = 29248;    // = 58496/2
constexpr int F_O   = F_BASE;        // o / dz shared, [8][68]
constexpr int F_XH  = F_BASE + 544;
constexpr int F_GD  = F_XH + 544;
constexpr int F_TGL = F_GD + 544;    // tgl - c1, [8][68]
constexpr int F_B1  = F_TGL + 544;
constexpr int F_B2  = F_B1 + 64;
constexpr int F_LG  = F_B2 + 64;
constexpr int F_LB  = F_LG + 64;
constexpr int F_C1  = F_LB + 64;     // Lb @ Lw^T (static)
constexpr int F_TGm = F_C1 + 64;
constexpr int F_TBm = F_TGm + 64;
constexpr int F_RSTD = F_TBm + 64;
constexpr int U_KG  = (F_RSTD + 8) * 2;   // -LR*K*K^T, [16][hi8|lo8] = 63760
constexpr int U_HT2 = U_KG + 256;         // HT buffer 1
constexpr int LDS_BYTES = (U_HT2 + 1024) * 2;   // 130080 B

// ---------------------------------------------------------------------------
// Helpers
// ---------------------------------------------------------------------------
__device__ __forceinline__ short bf_rn(float v) {
    unsigned u = __float_as_uint(v);
    unsigned r = u + 0x7fffu + ((u >> 16) & 1u);   // round-to-nearest-even
    return (short)(r >> 16);
}
__device__ __forceinline__ void cvt1(float v, short &hi, short &lo) {
    hi = bf_rn(v);
    float hf = __uint_as_float(((unsigned)(unsigned short)hi) << 16);
    lo = bf_rn(v - hf);
}
__device__ __forceinline__ float bf2f(short u) {
    return __uint_as_float(((unsigned)(unsigned short)u) << 16);
}
// Packed bf16 pair conversion: 1 instruction converts 2 floats (RTNE).
__device__ __forceinline__ unsigned cvtpk(float a, float b) {
    unsigned r;
    asm("v_cvt_pk_bf16_f32 %0, %1, %2" : "=v"(r) : "v"(a), "v"(b));
    return r;                      // lo16 = bf16(a), hi16 = bf16(b)
}
// hi/lo split of a float pair: hw = packed hi-bf16s, lw = packed lo-bf16s.
__device__ __forceinline__ void cvt2(float a, float b, unsigned &hw,
                                     unsigned &lw) {
    hw = cvtpk(a, b);
    float ra = a - __uint_as_float(hw << 16);
    float rb = b - __uint_as_float(hw & 0xffff0000u);
    lw = cvtpk(ra, rb);
}
// DPP-based 32-lane sum: 4 VALU-speed DPP adds + 1 cross-row swizzle.
template <int CTRL>
__device__ __forceinline__ float dpp_add(float v) {
    int s = __builtin_amdgcn_update_dpp(0, __float_as_int(v), CTRL, 0xF, 0xF,
                                        true);
    return v + __int_as_float(s);
}
__device__ __forceinline__ float red32(float v) {
    v = dpp_add<0xB1>(v);    // quad_perm [1,0,3,2]  (xor 1)
    v = dpp_add<0x4E>(v);    // quad_perm [2,3,0,1]  (xor 2)
    v = dpp_add<0x124>(v);   // row_ror:4
    v = dpp_add<0x128>(v);   // row_ror:8
    v += __shfl_xor(v, 16);  // merge the two 16-rows of the 32-group
    return v;
}
__device__ __forceinline__ float fast_tanh(float u) {
    u = fminf(fmaxf(u, -10.f), 10.f);
    float e = __expf(2.0f * u);
    return (e - 1.0f) / (e + 1.0f);
}
__device__ __forceinline__ void gelu_both(float x, float &g, float &dg) {
    const float C0 = 0.7978845608028654f, A0 = 0.044715f;
    float x2 = x * x;
    float u = C0 * x * (1.0f + A0 * x2);
    float t = fast_tanh(u);
    g = 0.5f * x * (1.0f + t);
    float du = C0 * (1.0f + 3.0f * A0 * x2);
    dg = 0.5f * (1.0f + t) + 0.5f * x * (1.0f - t * t) * du;
}
__device__ __forceinline__ float gelu_f(float x) {
    const float C0 = 0.7978845608028654f, A0 = 0.044715f;
    float u = C0 * x * (1.0f + A0 * x * x);
    return 0.5f * x * (1.0f + fast_tanh(u));
}

// C[16x16 tile w] = A(16x64, row planes) @ B(64x64 via n-major planes)
__device__ __forceinline__ f32x4 mm64(const unsigned short *Ap,
                                      const unsigned short *Bp,
                                      int w, int c, int q) {
    const unsigned short *ar = Ap + c * 136 + 8 * q;
    const unsigned short *br = Bp + (16 * w + c) * 136 + 8 * q;
    bf16x8 ah0 = *(const bf16x8 *)(ar);
    bf16x8 al0 = *(const bf16x8 *)(ar + 64);
    bf16x8 bh0 = *(const bf16x8 *)(br);
    bf16x8 bl0 = *(const bf16x8 *)(br + 64);
    bf16x8 ah1 = *(const bf16x8 *)(ar + 32);
    bf16x8 al1 = *(const bf16x8 *)(ar + 96);
    bf16x8 bh1 = *(const bf16x8 *)(br + 32);
    bf16x8 bl1 = *(const bf16x8 *)(br + 96);
    f32x4 x0 = {0.f, 0.f, 0.f, 0.f}, x1 = {0.f, 0.f, 0.f, 0.f};
    x0 = MFMA16(ah0, bh0, x0); x1 = MFMA16(ah1, bh1, x1);
    x0 = MFMA16(al0, bh0, x0); x1 = MFMA16(al1, bh1, x1);
    x0 = MFMA16(ah0, bl0, x0); x1 = MFMA16(ah1, bl1, x1);
    x0 = MFMA16(al0, bl0, x0); x1 = MFMA16(al1, bl1, x1);
    return x0 + x1;
}

// W(tile col n=16w+c) -= LR * X^T@Y ; X,Y given as T-arrays [64][b:8|8] bf16.
// Packed-K: one MFMA per 16-row block computes hh+lh+hl via K-chunks
// (q0: Xhi*Yhi, q1: Xlo*Yhi, q2: Xhi*Ylo, q3: 0).
__device__ __forceinline__ void updW(const unsigned short *XT,
                                     const unsigned short *YT,
                                     unsigned short *WT,
                                     int w, int c, int q) {
    bf16x8 zf;
#pragma unroll
    for (int j = 0; j < 8; ++j) zf[j] = 0;
    bf16x8 b = zf;
    if (q < 2)
        b = *(const bf16x8 *)&YT[(16 * w + c) * 16];
    else if (q == 2)
        b = *(const bf16x8 *)&YT[(16 * w + c) * 16 + 8];
    f32x4 g[4];
#pragma unroll
    for (int mt = 0; mt < 4; ++mt) {
        bf16x8 a = *(const bf16x8 *)&XT[(16 * mt + c) * 16 + (q & 1) * 8];
        f32x4 z = {0.f, 0.f, 0.f, 0.f};
        g[mt] = MFMA16(a, b, z);
    }
#pragma unroll
    for (int mt = 0; mt < 4; ++mt) {
        unsigned short *ph = &WT[(16 * w + c) * 136 + 16 * mt + 4 * q];
        unsigned short *pl = ph + 64;
        uint2 oh = *(uint2 *)ph, ol = *(uint2 *)pl;
        float v0 = __uint_as_float(oh.x << 16) +
                   __uint_as_float(ol.x << 16) - LR * g[mt][0];
        float v1 = __uint_as_float(oh.x & 0xffff0000u) +
                   __uint_as_float(ol.x & 0xffff0000u) - LR * g[mt][1];
        float v2 = __uint_as_float(oh.y << 16) +
                   __uint_as_float(ol.y << 16) - LR * g[mt][2];
        float v3 = __uint_as_float(oh.y & 0xffff0000u) +
                   __uint_as_float(ol.y & 0xffff0000u) - LR * g[mt][3];
        unsigned nh0, nl0, nh1, nl1;
        cvt2(v0, v1, nh0, nl0);
        cvt2(v2, v3, nh1, nl1);
        uint2 nh, nl;
        nh.x = nh0; nh.y = nh1;
        nl.x = nl0; nl.y = nl1;
        *(uint2 *)ph = nh;
        *(uint2 *)pl = nl;
    }
}

// acc1 += (-LR*Kg) @ da : one MFMA, A = KgT [16][hi8|lo8], B = DAT rows
// 16w+c (same-wave written). K-chunk packing as in updW (hh, lh, hl, 0).
__device__ __forceinline__ f32x4 accupd(const unsigned short *KgT,
                                        const unsigned short *DATp,
                                        f32x4 acc1, int w, int c, int q) {
    bf16x8 zf;
#pragma unroll
    for (int j = 0; j < 8; ++j) zf[j] = 0;
    bf16x8 b = zf;
    if (q < 2)
        b = *(const bf16x8 *)&DATp[(16 * w + c) * 16];
    else if (q == 2)
        b = *(const bf16x8 *)&DATp[(16 * w + c) * 16 + 8];
    bf16x8 a = *(const bf16x8 *)&KgT[c * 16 + (q & 1) * 8];
    return MFMA16(a, b, acc1);
}

// ---------------------------------------------------------------------------
// TTT scan kernel: one block (256 thr = 4 waves) per head
// Phase plan per token (22 barriers):
//   F1o (acc1=k@W1, Kg, TGL, gelu) | 4x{ F2 | LNf | B1' | LNb | B2+upd+F1' }
//   | F2fin(+stage t+1) | epilogue(no barrier)
// F1' = incremental acc1 MFMA + gelu (step3 instance IS the final forward).
// ---------------------------------------------------------------------------
__global__ __launch_bounds__(256) void ttt_scan(
    const float *__restrict__ q_g, const float *__restrict__ k_g,
    const float *__restrict__ v_g, float *__restrict__ out_g,
    const float *__restrict__ fw_w1, const float *__restrict__ fw_b1,
    const float *__restrict__ fw_w2, const float *__restrict__ fw_b2,
    const float *__restrict__ fw_lng, const float *__restrict__ fw_lnb,
    const float *__restrict__ loss_w, const float *__restrict__ loss_bv,
    const float *__restrict__ ttt_gv, const float *__restrict__ ttt_bv) {
    extern __shared__ char smem[];
    unsigned short *us = (unsigned short *)smem;
    float *fs = (float *)smem;

    unsigned short *W1T = us + U_W1T, *W2T = us + U_W2T, *W2R = us + U_W2R;
    unsigned short *Gp = us + U_G, *LwR = us + U_LwR;
    unsigned short *Kp = us + U_K, *Hp = us + U_H, *Zp = us + U_Z;
    unsigned short *TGp = us + U_TG, *DOp = us + U_DO;
    unsigned short *KT = us + U_KT, *HT0 = us + U_HT;
    unsigned short *DOT = us + U_DOT, *DAT = us + U_DAT;
    unsigned short *KgT = us + U_KG, *HT1 = us + U_HT2;
    float *o_s = fs + F_O, *xh_s = fs + F_XH, *gd_s = fs + F_GD;
    float *TGL = fs + F_TGL;
    float *b1_s = fs + F_B1, *b2_s = fs + F_B2, *lg_s = fs + F_LG;
    float *lb_s = fs + F_LB, *c1_s = fs + F_C1;
    float *tG_s = fs + F_TGm, *tB_s = fs + F_TBm, *rstd_s = fs + F_RSTD;

    const int h = blockIdx.x, tid = threadIdx.x;
    const int w = tid >> 6, lane = tid & 63, c = lane & 15, q = lane >> 4;
    const int bb = tid >> 5, j0 = (tid & 31) * 2;

    // ---- init: split weights into bf16 hi/lo planes
    for (int i = tid; i < 4096; i += 256) {
        int r = i >> 6, cc = i & 63;
        short hi, lo;
        cvt1(fw_w1[h * 4096 + i], hi, lo);           // [d=r][f=cc]
        W1T[cc * 136 + r] = (unsigned short)hi;
        W1T[cc * 136 + 64 + r] = (unsigned short)lo;
        cvt1(fw_w2[h * 4096 + i], hi, lo);           // [f=r][d=cc]
        W2T[cc * 136 + r] = (unsigned short)hi;
        W2T[cc * 136 + 64 + r] = (unsigned short)lo;
        W2R[r * 136 + cc] = (unsigned short)hi;
        W2R[r * 136 + 64 + cc] = (unsigned short)lo;
        cvt1(loss_w[i], hi, lo);                     // [d=r][e=cc]
        LwR[r * 136 + cc] = (unsigned short)hi;
        LwR[r * 136 + 64 + cc] = (unsigned short)lo;
    }
    // zero pad rows 8..15 of the 5 activation row-plane arrays
    for (int i = tid; i < 5 * 8 * 128; i += 256) {
        int a = i / 128, u = i % 128;
        int arr = a >> 3, row = 8 + (a & 7);
        unsigned short *base = (arr == 0) ? Kp : (arr == 1) ? Hp
                              : (arr == 2) ? Zp : (arr == 3) ? TGp : DOp;
        base[row * 136 + u] = 0;
    }
    __syncthreads();
    // G = Lw @ Lw^T (static; fuses F3+B1 into one phase per step)
#pragma unroll 1
    for (int mt = 0; mt < 4; ++mt) {
        f32x4 g = mm64(LwR + 16 * 136 * mt, LwR, w, c, q);
#pragma unroll
        for (int r = 0; r < 4; ++r) {
            short hi, lo;
            cvt1(g[r], hi, lo);
            int dr = 16 * mt + 4 * q + r, dc = 16 * w + c;
            Gp[dr * 136 + dc] = (unsigned short)hi;
            Gp[dr * 136 + 64 + dc] = (unsigned short)lo;
        }
    }
    if (tid < 64) {
        b1_s[tid] = fw_b1[h * 64 + tid];
        b2_s[tid] = fw_b2[h * 64 + tid];
        lg_s[tid] = fw_lng[h * 64 + tid];
        lb_s[tid] = fw_lnb[h * 64 + tid];
        tG_s[tid] = ttt_gv[h * 64 + tid];
        tB_s[tid] = ttt_bv[h * 64 + tid];
        float c1 = 0.f;                      // c1[d] = sum_e Lb[e]*Lw[d,e]
        for (int e = 0; e < 64; ++e) c1 += loss_bv[e] * loss_w[tid * 64 + e];
        c1_s[tid] = c1;
    }

    // ---- stage token 0 (Kp/KT/TGp) and hold q(0) in registers
    float2 pk, pv, pq, q_cur;
    {
        int idx = ((bb * Sv + 0) * Hv + h) * Dv + j0;
        float2 k0 = *(const float2 *)&k_g[idx];
        float2 v0 = *(const float2 *)&v_g[idx];
        q_cur = *(const float2 *)&q_g[idx];
        unsigned khw, klw;
        cvt2(k0.x, k0.y, khw, klw);
        *(unsigned *)&Kp[bb * 136 + j0] = khw;
        *(unsigned *)&Kp[bb * 136 + 64 + j0] = klw;
        KT[j0 * 16 + bb] = (unsigned short)khw;
        KT[j0 * 16 + 8 + bb] = (unsigned short)klw;
        KT[(j0 + 1) * 16 + bb] = (unsigned short)(khw >> 16);
        KT[(j0 + 1) * 16 + 8 + bb] = (unsigned short)(klw >> 16);
        unsigned thw, tlw;
        cvt2(v0.x - k0.x, v0.y - k0.y, thw, tlw);
        *(unsigned *)&TGp[bb * 136 + j0] = thw;
        *(unsigned *)&TGp[bb * 136 + 64 + j0] = tlw;
    }
    __syncthreads();

#pragma unroll 1
    for (int t = 0; t < Sv; ++t) {
        // issue prefetch for token t+1 (consumed at F2fin staging / epilogue)
        if (t + 1 < Sv) {
            int idx2 = ((bb * Sv + t + 1) * Hv + h) * Dv + j0;
            pk = *(const float2 *)&k_g[idx2];
            pv = *(const float2 *)&v_g[idx2];
            pq = *(const float2 *)&q_g[idx2];
        }

        // ---- F1o: acc1 = k@W1 (kept in regs all token); TGL; Kg; gelu
        f32x4 acc1 = mm64(Kp, W1T, w, c, q);
        {
            f32x4 a2 = mm64(TGp, LwR, w, c, q);
            if (q < 2) {
                int col = 16 * w + c;
#pragma unroll
                for (int r = 0; r < 4; ++r)
                    TGL[(4 * q + r) * 68 + col] = a2[r] - c1_s[col];
            }
        }
        if (w == 0) {
            // Kg = K@K^T (rows/cols >=8 are zero via Kp padding); store -LR*Kg
            f32x4 kg = mm64(Kp, Kp, 0, c, q);
            if (q < 2) {
#pragma unroll
                for (int r = 0; r < 4; ++r) {
                    short hi, lo;
                    cvt1(-LR * kg[r], hi, lo);
                    KgT[c * 16 + 4 * q + r] = (unsigned short)hi;
                    KgT[c * 16 + 8 + 4 * q + r] = (unsigned short)lo;
                }
            }
        }
        if (q < 2) {
            int col = 16 * w + c;
            float bias = b1_s[col];
            float gv[4];
#pragma unroll
            for (int r = 0; r < 4; ++r) {
                float g, dg;
                gelu_both(acc1[r] + bias, g, dg);
                gv[r] = g;
                gd_s[(4 * q + r) * 68 + col] = dg;
            }
            unsigned h01, l01, h23, l23;
            cvt2(gv[0], gv[1], h01, l01);
            cvt2(gv[2], gv[3], h23, l23);
            Hp[(4 * q + 0) * 136 + col] = (unsigned short)h01;
            Hp[(4 * q + 1) * 136 + col] = (unsigned short)(h01 >> 16);
            Hp[(4 * q + 2) * 136 + col] = (unsigned short)h23;
            Hp[(4 * q + 3) * 136 + col] = (unsigned short)(h23 >> 16);
            Hp[(4 * q + 0) * 136 + 64 + col] = (unsigned short)l01;
            Hp[(4 * q + 1) * 136 + 64 + col] = (unsigned short)(l01 >> 16);
            Hp[(4 * q + 2) * 136 + 64 + col] = (unsigned short)l23;
            Hp[(4 * q + 3) * 136 + 64 + col] = (unsigned short)(l23 >> 16);
            uint2 hh, hl;
            hh.x = h01; hh.y = h23;
            hl.x = l01; hl.y = l23;
            *(uint2 *)&HT0[col * 16 + 4 * q] = hh;
            *(uint2 *)&HT0[col * 16 + 8 + 4 * q] = hl;
        }
        __syncthreads();

#pragma unroll 1
        for (int step = 0; step < 4; ++step) {
            const unsigned short *HTr = (step & 1) ? HT1 : HT0;
            unsigned short *HTw = (step & 1) ? HT0 : HT1;
            // F2: o = h@W2 + b2
            f32x4 acc = mm64(Hp, W2T, w, c, q);
            if (q < 2) {
                float bias = b2_s[16 * w + c];
#pragma unroll
                for (int r = 0; r < 4; ++r)
                    o_s[(4 * q + r) * 68 + 16 * w + c] = acc[r] + bias;
            }
            __syncthreads();
            // LN fwd (thread-mapped); xh kept in regs for LNb
            float xh0_r, xh1_r;
            {
                float2 xv = *(const float2 *)&o_s[bb * 68 + j0];
                float mu = red32(xv.x + xv.y) * (1.f / 64.f);
                float d0 = xv.x - mu, d1 = xv.y - mu;
                float var = red32(d0 * d0 + d1 * d1) * (1.f / 64.f);
                float rs = rsqrtf(var + 1e-5f);
                float xh0 = d0 * rs, xh1 = d1 * rs;
                float2 xw; xw.x = xh0; xw.y = xh1;
                *(float2 *)&xh_s[bb * 68 + j0] = xw;
                float z0 = xh0 * lg_s[j0] + lb_s[j0];
                float z1 = xh1 * lg_s[j0 + 1] + lb_s[j0 + 1];
                unsigned zh, zl;
                cvt2(z0, z1, zh, zl);
                *(unsigned *)&Zp[bb * 136 + j0] = zh;
                *(unsigned *)&Zp[bb * 136 + 64 + j0] = zl;
                if ((tid & 31) == 0) rstd_s[bb] = rs;
                xh0_r = xh0; xh1_r = xh1;
            }
            __syncthreads();
            // B1' (fused F3+B1): dz = SCALE * (z@G - (tgl - c1))
            acc = mm64(Zp, Gp, w, c, q);
            if (q < 2) {
                int col = 16 * w + c;
#pragma unroll
                for (int r = 0; r < 4; ++r) {
                    int row = 4 * q + r;
                    o_s[row * 68 + col] =
                        (acc[r] - TGL[row * 68 + col]) * SCALE;
                }
            }
            __syncthreads();
            // LN bwd (thread-mapped) -> do planes + doT
            {
                float2 dzv = *(const float2 *)&o_s[bb * 68 + j0];
                float dxh0 = dzv.x * lg_s[j0], dxh1 = dzv.y * lg_s[j0 + 1];
                float S1 = red32(dxh0 + dxh1) * (1.f / 64.f);
                float S2 = red32(dxh0 * xh0_r + dxh1 * xh1_r) * (1.f / 64.f);
                float rs = rstd_s[bb];
                float do0 = rs * (dxh0 - S1 - xh0_r * S2);
                float do1 = rs * (dxh1 - S1 - xh1_r * S2);
                unsigned dh, dl;
                cvt2(do0, do1, dh, dl);
                *(unsigned *)&DOp[bb * 136 + j0] = dh;
                *(unsigned *)&DOp[bb * 136 + 64 + j0] = dl;
                DOT[j0 * 16 + bb] = (unsigned short)dh;
                DOT[j0 * 16 + 8 + bb] = (unsigned short)dl;
                DOT[(j0 + 1) * 16 + bb] = (unsigned short)(dh >> 16);
                DOT[(j0 + 1) * 16 + 8 + bb] = (unsigned short)(dl >> 16);
            }
            __syncthreads();
            // B2+upd+F1' (single phase): dh=do@W2^T; da->DAT; 3x updW;
            // vector params; then acc1 += (-LR*Kg)@da (one MFMA) and gelu
            // (step3 instance IS the final forward h).
            acc = mm64(DOp, W2R, w, c, q);
            {
                float b1sum = 0.f;
                if (q < 2) {
                    int col = 16 * w + c;
                    float da0 = acc[0] * gd_s[(4 * q + 0) * 68 + col];
                    float da1 = acc[1] * gd_s[(4 * q + 1) * 68 + col];
                    float da2 = acc[2] * gd_s[(4 * q + 2) * 68 + col];
                    float da3 = acc[3] * gd_s[(4 * q + 3) * 68 + col];
                    b1sum = da0 + da1 + da2 + da3;
                    unsigned h01, l01, h23, l23;
                    cvt2(da0, da1, h01, l01);
                    cvt2(da2, da3, h23, l23);
                    uint2 th, tl;
                    th.x = h01; th.y = h23;
                    tl.x = l01; tl.y = l23;
                    *(uint2 *)&DAT[col * 16 + 4 * q] = th;
                    *(uint2 *)&DAT[col * 16 + 8 + 4 * q] = tl;
                }
                b1sum += __shfl_xor(b1sum, 16);
                updW(KT, DAT, W1T, w, c, q);
                updW(HTr, DOT, W2T, w, c, q);
                updW(DOT, HTr, W2R, w, c, q);
                if (w == 2) {
                    bf16x8 oh_ = *(const bf16x8 *)&DOT[lane * 16];
                    bf16x8 ol_ = *(const bf16x8 *)&DOT[lane * 16 + 8];
                    float db2 = 0.f;
#pragma unroll
                    for (int j = 0; j < 8; ++j)
                        db2 += bf2f(oh_[j]) + bf2f(ol_[j]);
                    b2_s[lane] -= LR * db2;
                } else if (w == 3) {
                    float dlb = 0.f, dlg = 0.f;
#pragma unroll
                    for (int b = 0; b < 8; ++b) {
                        float dzv = o_s[b * 68 + lane];
                        dlb += dzv;
                        dlg += dzv * xh_s[b * 68 + lane];
                    }
                    lb_s[lane] -= LR * dlb;
                    lg_s[lane] -= LR * dlg;
                }
                // F1': incremental pre-activation + activation for next step
                acc1 = accupd(KgT, DAT, acc1, w, c, q);
                if (q < 2) {
                    int col = 16 * w + c;
                    float b1v = b1_s[col] - LR * b1sum;
                    if (q == 0) b1_s[col] = b1v;
                    if (step < 3) {
                        float gv[4];
#pragma unroll
                        for (int r = 0; r < 4; ++r) {
                            float g, dg;
                            gelu_both(acc1[r] + b1v, g, dg);
                            gv[r] = g;
                            gd_s[(4 * q + r) * 68 + col] = dg;
                        }
                        unsigned h01, l01, h23, l23;
                        cvt2(gv[0], gv[1], h01, l01);
                        cvt2(gv[2], gv[3], h23, l23);
                        Hp[(4 * q + 0) * 136 + col] = (unsigned short)h01;
                        Hp[(4 * q + 1) * 136 + col] = (unsigned short)(h01 >> 16);
                        Hp[(4 * q + 2) * 136 + col] = (unsigned short)h23;
                        Hp[(4 * q + 3) * 136 + col] = (unsigned short)(h23 >> 16);
                        Hp[(4 * q + 0) * 136 + 64 + col] = (unsigned short)l01;
                        Hp[(4 * q + 1) * 136 + 64 + col] = (unsigned short)(l01 >> 16);
                        Hp[(4 * q + 2) * 136 + 64 + col] = (unsigned short)l23;
                        Hp[(4 * q + 3) * 136 + 64 + col] = (unsigned short)(l23 >> 16);
                        uint2 hh, hl;
                        hh.x = h01; hh.y = h23;
                        hl.x = l01; hl.y = l23;
                        *(uint2 *)&HTw[col * 16 + 4 * q] = hh;
                        *(uint2 *)&HTw[col * 16 + 8 + 4 * q] = hl;
                    } else {
                        // final forward h (feeds F2fin); no HT/gd needed
                        float gv[4];
#pragma unroll
                        for (int r = 0; r < 4; ++r)
                            gv[r] = gelu_f(acc1[r] + b1v);
                        unsigned h01, l01, h23, l23;
                        cvt2(gv[0], gv[1], h01, l01);
                        cvt2(gv[2], gv[3], h23, l23);
                        Hp[(4 * q + 0) * 136 + col] = (unsigned short)h01;
                        Hp[(4 * q + 1) * 136 + col] = (unsigned short)(h01 >> 16);
                        Hp[(4 * q + 2) * 136 + col] = (unsigned short)h23;
                        Hp[(4 * q + 3) * 136 + col] = (unsigned short)(h23 >> 16);
                        Hp[(4 * q + 0) * 136 + 64 + col] = (unsigned short)l01;
                        Hp[(4 * q + 1) * 136 + 64 + col] = (unsigned short)(l01 >> 16);
                        Hp[(4 * q + 2) * 136 + 64 + col] = (unsigned short)l23;
                        Hp[(4 * q + 3) * 136 + 64 + col] = (unsigned short)(l23 >> 16);
                    }
                }
            }
            __syncthreads();
        }

        // ---- F2fin: o = h_final@W2 + b2 ; stage token t+1 (Kp/KT/TGp)
        f32x4 acc = mm64(Hp, W2T, w, c, q);
        if (q < 2) {
            float bias = b2_s[16 * w + c];
#pragma unroll
            for (int r = 0; r < 4; ++r)
                o_s[(4 * q + r) * 68 + 16 * w + c] = acc[r] + bias;
        }
        if (t + 1 < Sv) {
            unsigned khw, klw;
            cvt2(pk.x, pk.y, khw, klw);
            *(unsigned *)&Kp[bb * 136 + j0] = khw;
            *(unsigned *)&Kp[bb * 136 + 64 + j0] = klw;
            KT[j0 * 16 + bb] = (unsigned short)khw;
            KT[j0 * 16 + 8 + bb] = (unsigned short)klw;
            KT[(j0 + 1) * 16 + bb] = (unsigned short)(khw >> 16);
            KT[(j0 + 1) * 16 + 8 + bb] = (unsigned short)(klw >> 16);
            unsigned thw, tlw;
            cvt2(pv.x - pk.x, pv.y - pk.y, thw, tlw);
            *(unsigned *)&TGp[bb * 136 + j0] = thw;
            *(unsigned *)&TGp[bb * 136 + 64 + j0] = tlw;
        }
        __syncthreads();
        // epilogue: LN(lg,lb) -> LN(ttt_g,ttt_b) -> out = q + z2
        // (no trailing barrier: F1o's end-barrier orders the o_s reuse)
        {
            float2 xv = *(const float2 *)&o_s[bb * 68 + j0];
            float mu = red32(xv.x + xv.y) * (1.f / 64.f);
            float d0 = xv.x - mu, d1 = xv.y - mu;
            float var = red32(d0 * d0 + d1 * d1) * (1.f / 64.f);
            float rs = rsqrtf(var + 1e-5f);
            float z0 = d0 * rs * lg_s[j0] + lb_s[j0];
            float z1 = d1 * rs * lg_s[j0 + 1] + lb_s[j0 + 1];
            float mu2 = red32(z0 + z1) * (1.f / 64.f);
            float e0 = z0 - mu2, e1 = z1 - mu2;
            float var2 = red32(e0 * e0 + e1 * e1) * (1.f / 64.f);
            float rs2 = rsqrtf(var2 + 1e-5f);
            float z20 = e0 * rs2 * tG_s[j0] + tB_s[j0];
            float z21 = e1 * rs2 * tG_s[j0 + 1] + tB_s[j0 + 1];
            int idx = ((bb * Sv + t) * Hv + h) * Dv + j0;
            float2 ov;
            ov.x = q_cur.x + z20;
            ov.y = q_cur.y + z21;
            *(float2 *)&out_g[idx] = ov;
            q_cur = pq;
        }
    }
}

// ---------------------------------------------------------------------------
// fp32 GEMM: C[M,N] = A[M,K] @ B[K,N]; mode 1: C = gelu(acc) * gate_ln
// ---------------------------------------------------------------------------
__global__ __launch_bounds__(256) void gemm_f32(
    const float *__restrict__ A, const float *__restrict__ B,
    float *__restrict__ C, const float *__restrict__ gate_ln,
    int M, int N, int K, int mode) {
    __shared__ float As[16][68];
    __shared__ float Bs[16][64];
    const int tid = threadIdx.x;
    const int tx = tid & 15, ty = tid >> 4;
    const int bm = blockIdx.y * 64, bn = blockIdx.x * 64;

    float acc[4][4] = {};
    for (int k0 = 0; k0 < K; k0 += 16) {
        {
            int r = tid >> 2, kk = (tid & 3) * 4;
            float4 av = *(const float4 *)(A + (long)(bm + r) * K + k0 + kk);
            As[kk + 0][r] = av.x;
            As[kk + 1][r] = av.y;
            As[kk + 2][r] = av.z;
            As[kk + 3][r] = av.w;
            int rr = tid >> 4, cc = (tid & 15) * 4;
            float4 bv = *(const float4 *)(B + (long)(k0 + rr) * N + bn + cc);
            *(float4 *)&Bs[rr][cc] = bv;
        }
        __syncthreads();
#pragma unroll
        for (int kk = 0; kk < 16; ++kk) {
            float4 a4 = *(float4 *)&As[kk][ty * 4];
            float4 b4 = *(float4 *)&Bs[kk][tx * 4];
            float a[4] = {a4.x, a4.y, a4.z, a4.w};
            float b[4] = {b4.x, b4.y, b4.z, b4.w};
#pragma unroll
            for (int i = 0; i < 4; ++i)
#pragma unroll
                for (int j = 0; j < 4; ++j) acc[i][j] += a[i] * b[j];
        }
        __syncthreads();
    }
#pragma unroll
    for (int i = 0; i < 4; ++i) {
        int row = bm + ty * 4 + i;
        float4 out;
        float v[4];
#pragma unroll
        for (int j = 0; j < 4; ++j) {
            float val = acc[i][j];
            if (mode == 1) {
                int col = bn + tx * 4 + j;
                val = gelu_f(val) * gate_ln[(long)row * N + col];
            }
            v[j] = val;
        }
        out.x = v[0]; out.y = v[1]; out.z = v[2]; out.w = v[3];
        *(float4 *)(C + (long)row * N + bn + tx * 4) = out;
    }
}

// ---------------------------------------------------------------------------
// Row LayerNorm over 1024 (post-scan, pn_g / pn_b)
// ---------------------------------------------------------------------------
__global__ __launch_bounds__(256) void row_ln(const float *__restrict__ in,
                                              float *__restrict__ out,
                                              const float *__restrict__ g,
                                              const float *__restrict__ b) {
    __shared__ float sred[4], s2red[4];
    const int row = blockIdx.x;
    const int tid = threadIdx.x;
    const float *x = in + (long)row * 1024;
    float4 v = *(const float4 *)(x + tid * 4);
    float s = v.x + v.y + v.z + v.w;
    float s2 = v.x * v.x + v.y * v.y + v.z * v.z + v.w * v.w;
#pragma unroll
    for (int m = 1; m <= 32; m <<= 1) {
        s += __shfl_xor(s, m);
        s2 += __shfl_xor(s2, m);
    }
    if ((tid & 63) == 0) {
        sred[tid >> 6] = s;
        s2red[tid >> 6] = s2;
    }
    __syncthreads();
    float S = sred[0] + sred[1] + sred[2] + sred[3];
    float S2 = s2red[0] + s2red[1] + s2red[2] + s2red[3];
    float mu = S * (1.f / 1024.f);
    float var = S2 * (1.f / 1024.f) - mu * mu;
    float rs = rsqrtf(var + 1e-5f);
    float o[4] = {v.x, v.y, v.z, v.w};
    float4 ov;
    float r[4];
#pragma unroll
    for (int i = 0; i < 4; ++i) {
        int col = tid * 4 + i;
        r[i] = (o[i] - mu) * rs * g[col] + b[col];
    }
    ov.x = r[0]; ov.y = r[1]; ov.z = r[2]; ov.w = r[3];
    *(float4 *)(out + (long)row * 1024 + tid * 4) = ov;
}

// ---------------------------------------------------------------------------
// Launch
// ---------------------------------------------------------------------------
extern "C" void kernel_launch(void *const *d_in, const int *in_sizes, int n_in,
                              void *d_out, int out_size, void *d_ws,
                              size_t ws_size, hipStream_t stream) {
    const float *x = (const float *)d_in[0];
    const float *wq = (const float *)d_in[1];
    const float *wk = (const float *)d_in[2];
    const float *wv = (const float *)d_in[3];
    const float *fw_w1 = (const float *)d_in[4];
    const float *fw_b1 = (const float *)d_in[5];
    const float *fw_w2 = (const float *)d_in[6];
    const float *fw_b2 = (const float *)d_in[7];
    const float *fw_lng = (const float *)d_in[8];
    const float *fw_lnb = (const float *)d_in[9];
    const float *loss_w = (const float *)d_in[10];
    const float *loss_b = (const float *)d_in[11];
    const float *ttt_g = (const float *)d_in[12];
    const float *ttt_b = (const float *)d_in[13];
    const float *wo = (const float *)d_in[14];
    const float *wg = (const float *)d_in[15];
    const float *pn_g = (const float *)d_in[16];
    const float *pn_b = (const float *)d_in[17];

    const long MAT = 2048L * 1024L;
    float *q_ws = (float *)d_ws;
    float *k_ws = q_ws + MAT;
    float *v_ws = k_ws + MAT;
    float *out_ws = v_ws + MAT;
    float *ln_ws = k_ws;       // reuse (k dead after scan)
    float *gated_ws = v_ws;    // reuse (v dead after scan)

    dim3 gg(1024 / 64, 2048 / 64), bt(256);
    hipLaunchKernelGGL(gemm_f32, gg, bt, 0, stream, x, wq, q_ws,
                       (const float *)nullptr, 2048, 1024, 1024, 0);
    hipLaunchKernelGGL(gemm_f32, gg, bt, 0, stream, x, wk, k_ws,
                       (const float *)nullptr, 2048, 1024, 1024, 0);
    hipLaunchKernelGGL(gemm_f32, gg, bt, 0, stream, x, wv, v_ws,
                       (const float *)nullptr, 2048, 1024, 1024, 0);

    (void)hipFuncSetAttribute((const void *)ttt_scan,
                              hipFuncAttributeMaxDynamicSharedMemorySize,
                              LDS_BYTES);
    hipLaunchKernelGGL(ttt_scan, dim3(16), dim3(256), LDS_BYTES, stream,
                       q_ws, k_ws, v_ws, out_ws, fw_w1, fw_b1, fw_w2, fw_b2,
                       fw_lng, fw_lnb, loss_w, loss_b, ttt_g, ttt_b);

    hipLaunchKernelGGL(row_ln, dim3(2048), dim3(256), 0, stream, out_ws, ln_ws,
                       pn_g, pn_b);
    hipLaunchKernelGGL(gemm_f32, gg, bt, 0, stream, x, wg, gated_ws, ln_ws,
                       2048, 1024, 1024, 1);
    hipLaunchKernelGGL(gemm_f32, gg, bt, 0, stream, gated_ws, wo,
                       (float *)d_out, (const float *)nullptr, 2048, 1024,
                       1024, 0);
}

// Round 5
// 4235.660 us; speedup vs baseline: 1.4666x; 1.0790x over previous
//
#include <hip/hip_runtime.h>

// ---------------------------------------------------------------------------
// Problem constants
// ---------------------------------------------------------------------------
#define Bv 8
#define Sv 256
#define Hv 16
#define Dv 64
#define LR 0.1f
#define SCALE (2.0f / 8192.0f)   // dLoss/dpred scale: 2/(B*H*D)

using bf16x8 = __attribute__((ext_vector_type(8))) short;
using bf16x4 = __attribute__((ext_vector_type(4))) short;
using f32x4  = __attribute__((ext_vector_type(4))) float;
#define MFMA16(A, B, C) __builtin_amdgcn_mfma_f32_16x16x32_bf16(A, B, C, 0, 0, 0)

// ---------------------------------------------------------------------------
// LDS layout (ushort units for bf16 planes, float units for fp32 areas)
// Weight/row planes: pitch 136 ushort = 272 B (hi[64] | lo[64] | pad[8]).
// T arrays: pitch 16 ushort = 32 B (hi[8] | lo[8]).
// ---------------------------------------------------------------------------
constexpr int U_W1T = 0;          // [f][d] planes, 64x136
constexpr int U_W2T = 8704;      // [d][f]
constexpr int U_W2R = 17408;     // [f][d]
constexpr int U_G   = 26112;     // [d][d']  (symmetric, static)
constexpr int U_LwR = 34816;     // [d][e]   (static)
constexpr int U_K   = 43520;     // [b pad16][d] 16x136
constexpr int U_H   = 45696;     // [b][f]
constexpr int U_Z   = 47872;     // [b][d]
constexpr int U_TG  = 50048;     // [b pad16][e] target planes
constexpr int U_DO  = 52224;     // [b][d]
constexpr int U_KT  = 54400;     // [d][b] 64x16
constexpr int U_HT  = 55424;     // [f][b]  (buffer 0)
constexpr int U_DOT = 56448;     // [d][b]
constexpr int U_DAT = 57472;     // [f][b]
constexpr int F_BASE = 29248;    // = 58496/2
constexpr int F_O   = F_BASE;        // o / dz shared, [8][68]
constexpr int F_XH  = F_BASE + 544;
constexpr int F_GD  = F_XH + 544;    // (unused now - gd in regs)
constexpr int F_TGL = F_GD + 544;    // (unused now - tgl in regs)
constexpr int F_B1  = F_TGL + 544;   // (unused now - b1 in regs)
constexpr int F_B2  = F_B1 + 64;
constexpr int F_LG  = F_B2 + 64;
constexpr int F_LB  = F_LG + 64;
constexpr int F_C1  = F_LB + 64;     // Lb @ Lw^T (static)
constexpr int F_TGm = F_C1 + 64;
constexpr int F_TBm = F_TGm + 64;
constexpr int F_RSTD = F_TBm + 64;
constexpr int U_KG  = (F_RSTD + 8) * 2;   // -LR*K*K^T, [16][hi8|lo8]
constexpr int U_HT2 = U_KG + 256;         // HT buffer 1
constexpr int LDS_BYTES = (U_HT2 + 1024) * 2;   // 130080 B

// ---------------------------------------------------------------------------
// Helpers
// ---------------------------------------------------------------------------
__device__ __forceinline__ short bf_rn(float v) {
    unsigned u = __float_as_uint(v);
    unsigned r = u + 0x7fffu + ((u >> 16) & 1u);   // round-to-nearest-even
    return (short)(r >> 16);
}
__device__ __forceinline__ void cvt1(float v, short &hi, short &lo) {
    hi = bf_rn(v);
    float hf = __uint_as_float(((unsigned)(unsigned short)hi) << 16);
    lo = bf_rn(v - hf);
}
__device__ __forceinline__ float bf2f(short u) {
    return __uint_as_float(((unsigned)(unsigned short)u) << 16);
}
// Packed bf16 pair conversion: 1 instruction converts 2 floats (RTNE).
__device__ __forceinline__ unsigned cvtpk(float a, float b) {
    unsigned r;
    asm("v_cvt_pk_bf16_f32 %0, %1, %2" : "=v"(r) : "v"(a), "v"(b));
    return r;                      // lo16 = bf16(a), hi16 = bf16(b)
}
// hi/lo split of a float pair: hw = packed hi-bf16s, lw = packed lo-bf16s.
__device__ __forceinline__ void cvt2(float a, float b, unsigned &hw,
                                     unsigned &lw) {
    hw = cvtpk(a, b);
    float ra = a - __uint_as_float(hw << 16);
    float rb = b - __uint_as_float(hw & 0xffff0000u);
    lw = cvtpk(ra, rb);
}
// DPP-based 32-lane sum: 4 VALU-speed DPP adds + 1 cross-row swizzle.
template <int CTRL>
__device__ __forceinline__ float dpp_add(float v) {
    int s = __builtin_amdgcn_update_dpp(0, __float_as_int(v), CTRL, 0xF, 0xF,
                                        true);
    return v + __int_as_float(s);
}
__device__ __forceinline__ float red32(float v) {
    v = dpp_add<0xB1>(v);    // quad_perm [1,0,3,2]  (xor 1)
    v = dpp_add<0x4E>(v);    // quad_perm [2,3,0,1]  (xor 2)
    v = dpp_add<0x124>(v);   // row_ror:4
    v = dpp_add<0x128>(v);   // row_ror:8
    v += __shfl_xor(v, 16);  // merge the two 16-rows of the 32-group
    return v;
}
__device__ __forceinline__ float fast_tanh(float u) {
    u = fminf(fmaxf(u, -10.f), 10.f);
    float e = __expf(2.0f * u);
    return (e - 1.0f) / (e + 1.0f);
}
__device__ __forceinline__ void gelu_both(float x, float &g, float &dg) {
    const float C0 = 0.7978845608028654f, A0 = 0.044715f;
    float x2 = x * x;
    float u = C0 * x * (1.0f + A0 * x2);
    float t = fast_tanh(u);
    g = 0.5f * x * (1.0f + t);
    float du = C0 * (1.0f + 3.0f * A0 * x2);
    dg = 0.5f * (1.0f + t) + 0.5f * x * (1.0f - t * t) * du;
}
__device__ __forceinline__ float gelu_f(float x) {
    const float C0 = 0.7978845608028654f, A0 = 0.044715f;
    float u = C0 * x * (1.0f + A0 * x * x);
    return 0.5f * x * (1.0f + fast_tanh(u));
}

// C[16x16 tile w] = A(16x64, row planes) @ B(64x64 via n-major planes)
__device__ __forceinline__ f32x4 mm64(const unsigned short *Ap,
                                      const unsigned short *Bp,
                                      int w, int c, int q) {
    const unsigned short *ar = Ap + c * 136 + 8 * q;
    const unsigned short *br = Bp + (16 * w + c) * 136 + 8 * q;
    bf16x8 ah0 = *(const bf16x8 *)(ar);
    bf16x8 al0 = *(const bf16x8 *)(ar + 64);
    bf16x8 bh0 = *(const bf16x8 *)(br);
    bf16x8 bl0 = *(const bf16x8 *)(br + 64);
    bf16x8 ah1 = *(const bf16x8 *)(ar + 32);
    bf16x8 al1 = *(const bf16x8 *)(ar + 96);
    bf16x8 bh1 = *(const bf16x8 *)(br + 32);
    bf16x8 bl1 = *(const bf16x8 *)(br + 96);
    f32x4 x0 = {0.f, 0.f, 0.f, 0.f}, x1 = {0.f, 0.f, 0.f, 0.f};
    x0 = MFMA16(ah0, bh0, x0); x1 = MFMA16(ah1, bh1, x1);
    x0 = MFMA16(al0, bh0, x0); x1 = MFMA16(al1, bh1, x1);
    x0 = MFMA16(ah0, bl0, x0); x1 = MFMA16(ah1, bl1, x1);
    x0 = MFMA16(al0, bl0, x0); x1 = MFMA16(al1, bl1, x1);
    return x0 + x1;
}

// W(tile col n=16w+c) -= LR * X^T@Y with PRE-FETCHED operand fragments.
// a4[mt] = XT[(16mt+c)*16 + (q&1)*8]; b = YT row (16w+c) K-chunk packing
// (q0/q1: hi, q2: lo, q3: 0). W-tile loads issue before the MFMAs so their
// latency hides under the matrix ops (1 wave/SIMD -> nothing else hides it).
__device__ __forceinline__ void updW2(const bf16x8 *a4, bf16x8 b,
                                      unsigned short *WT, int w, int c,
                                      int q) {
    unsigned short *p0 = &WT[(16 * w + c) * 136 + 4 * q];
    uint2 oh[4], ol[4];
#pragma unroll
    for (int mt = 0; mt < 4; ++mt) {
        oh[mt] = *(uint2 *)(p0 + 16 * mt);
        ol[mt] = *(uint2 *)(p0 + 16 * mt + 64);
    }
    f32x4 g[4];
#pragma unroll
    for (int mt = 0; mt < 4; ++mt) {
        f32x4 z = {0.f, 0.f, 0.f, 0.f};
        g[mt] = MFMA16(a4[mt], b, z);
    }
#pragma unroll
    for (int mt = 0; mt < 4; ++mt) {
        float v0 = __uint_as_float(oh[mt].x << 16) +
                   __uint_as_float(ol[mt].x << 16) - LR * g[mt][0];
        float v1 = __uint_as_float(oh[mt].x & 0xffff0000u) +
                   __uint_as_float(ol[mt].x & 0xffff0000u) - LR * g[mt][1];
        float v2 = __uint_as_float(oh[mt].y << 16) +
                   __uint_as_float(ol[mt].y << 16) - LR * g[mt][2];
        float v3 = __uint_as_float(oh[mt].y & 0xffff0000u) +
                   __uint_as_float(ol[mt].y & 0xffff0000u) - LR * g[mt][3];
        unsigned nh0, nl0, nh1, nl1;
        cvt2(v0, v1, nh0, nl0);
        cvt2(v2, v3, nh1, nl1);
        uint2 nh, nl;
        nh.x = nh0; nh.y = nh1;
        nl.x = nl0; nl.y = nl1;
        *(uint2 *)(p0 + 16 * mt) = nh;
        *(uint2 *)(p0 + 16 * mt + 64) = nl;
    }
}

// ---------------------------------------------------------------------------
// TTT scan kernel: one block (256 thr = 4 waves) per head
// Phase plan per token (22 barriers):
//   F1o (acc1=k@W1, Kg, tgl_r, gelu) | 4x{ F2 | LNf | B1' | LNb | B2+upd+F1' }
//   | F2fin(+stage t+1) | epilogue(no barrier)
// Register-carried per lane: acc1, gd_r, tgl_r, b1_r, c1_r (+ xh in LN).
// ---------------------------------------------------------------------------
__global__ __launch_bounds__(256) void ttt_scan(
    const float *__restrict__ q_g, const float *__restrict__ k_g,
    const float *__restrict__ v_g, float *__restrict__ out_g,
    const float *__restrict__ fw_w1, const float *__restrict__ fw_b1,
    const float *__restrict__ fw_w2, const float *__restrict__ fw_b2,
    const float *__restrict__ fw_lng, const float *__restrict__ fw_lnb,
    const float *__restrict__ loss_w, const float *__restrict__ loss_bv,
    const float *__restrict__ ttt_gv, const float *__restrict__ ttt_bv) {
    extern __shared__ char smem[];
    unsigned short *us = (unsigned short *)smem;
    float *fs = (float *)smem;

    unsigned short *W1T = us + U_W1T, *W2T = us + U_W2T, *W2R = us + U_W2R;
    unsigned short *Gp = us + U_G, *LwR = us + U_LwR;
    unsigned short *Kp = us + U_K, *Hp = us + U_H, *Zp = us + U_Z;
    unsigned short *TGp = us + U_TG, *DOp = us + U_DO;
    unsigned short *KT = us + U_KT, *HT0 = us + U_HT;
    unsigned short *DOT = us + U_DOT, *DAT = us + U_DAT;
    unsigned short *KgT = us + U_KG, *HT1 = us + U_HT2;
    float *o_s = fs + F_O, *xh_s = fs + F_XH;
    float *b2_s = fs + F_B2, *lg_s = fs + F_LG;
    float *lb_s = fs + F_LB, *c1_s = fs + F_C1;
    float *tG_s = fs + F_TGm, *tB_s = fs + F_TBm, *rstd_s = fs + F_RSTD;

    const int h = blockIdx.x, tid = threadIdx.x;
    const int w = tid >> 6, lane = tid & 63, c = lane & 15, q = lane >> 4;
    const int bb = tid >> 5, j0 = (tid & 31) * 2;

    // ---- init: split weights into bf16 hi/lo planes
    for (int i = tid; i < 4096; i += 256) {
        int r = i >> 6, cc = i & 63;
        short hi, lo;
        cvt1(fw_w1[h * 4096 + i], hi, lo);           // [d=r][f=cc]
        W1T[cc * 136 + r] = (unsigned short)hi;
        W1T[cc * 136 + 64 + r] = (unsigned short)lo;
        cvt1(fw_w2[h * 4096 + i], hi, lo);           // [f=r][d=cc]
        W2T[cc * 136 + r] = (unsigned short)hi;
        W2T[cc * 136 + 64 + r] = (unsigned short)lo;
        W2R[r * 136 + cc] = (unsigned short)hi;
        W2R[r * 136 + 64 + cc] = (unsigned short)lo;
        cvt1(loss_w[i], hi, lo);                     // [d=r][e=cc]
        LwR[r * 136 + cc] = (unsigned short)hi;
        LwR[r * 136 + 64 + cc] = (unsigned short)lo;
    }
    // zero pad rows 8..15 of the 5 activation row-plane arrays
    for (int i = tid; i < 5 * 8 * 128; i += 256) {
        int a = i / 128, u = i % 128;
        int arr = a >> 3, row = 8 + (a & 7);
        unsigned short *base = (arr == 0) ? Kp : (arr == 1) ? Hp
                              : (arr == 2) ? Zp : (arr == 3) ? TGp : DOp;
        base[row * 136 + u] = 0;
    }
    __syncthreads();
    // G = Lw @ Lw^T (static; fuses F3+B1 into one phase per step)
#pragma unroll 1
    for (int mt = 0; mt < 4; ++mt) {
        f32x4 g = mm64(LwR + 16 * 136 * mt, LwR, w, c, q);
#pragma unroll
        for (int r = 0; r < 4; ++r) {
            short hi, lo;
            cvt1(g[r], hi, lo);
            int dr = 16 * mt + 4 * q + r, dc = 16 * w + c;
            Gp[dr * 136 + dc] = (unsigned short)hi;
            Gp[dr * 136 + 64 + dc] = (unsigned short)lo;
        }
    }
    if (tid < 64) {
        b2_s[tid] = fw_b2[h * 64 + tid];
        lg_s[tid] = fw_lng[h * 64 + tid];
        lb_s[tid] = fw_lnb[h * 64 + tid];
        tG_s[tid] = ttt_gv[h * 64 + tid];
        tB_s[tid] = ttt_bv[h * 64 + tid];
        float c1 = 0.f;                      // c1[d] = sum_e Lb[e]*Lw[d,e]
        for (int e = 0; e < 64; ++e) c1 += loss_bv[e] * loss_w[tid * 64 + e];
        c1_s[tid] = c1;
    }

    // ---- stage token 0 (Kp/KT/TGp) and hold q(0) in registers
    float2 pk, pv, pq, q_cur;
    {
        int idx = ((bb * Sv + 0) * Hv + h) * Dv + j0;
        float2 k0 = *(const float2 *)&k_g[idx];
        float2 v0 = *(const float2 *)&v_g[idx];
        q_cur = *(const float2 *)&q_g[idx];
        unsigned khw, klw;
        cvt2(k0.x, k0.y, khw, klw);
        *(unsigned *)&Kp[bb * 136 + j0] = khw;
        *(unsigned *)&Kp[bb * 136 + 64 + j0] = klw;
        KT[j0 * 16 + bb] = (unsigned short)khw;
        KT[j0 * 16 + 8 + bb] = (unsigned short)klw;
        KT[(j0 + 1) * 16 + bb] = (unsigned short)(khw >> 16);
        KT[(j0 + 1) * 16 + 8 + bb] = (unsigned short)(klw >> 16);
        unsigned thw, tlw;
        cvt2(v0.x - k0.x, v0.y - k0.y, thw, tlw);
        *(unsigned *)&TGp[bb * 136 + j0] = thw;
        *(unsigned *)&TGp[bb * 136 + 64 + j0] = tlw;
    }
    // register-carried params (per lane, q<2 lanes meaningful)
    float b1_r = (q < 2) ? fw_b1[h * 64 + 16 * w + c] : 0.f;
    __syncthreads();
    float c1_r = c1_s[16 * w + c];
    f32x4 gd_r = {0.f, 0.f, 0.f, 0.f};
    f32x4 tgl_r = {0.f, 0.f, 0.f, 0.f};

#pragma unroll 1
    for (int t = 0; t < Sv; ++t) {
        // issue prefetch for token t+1 (consumed at F2fin staging / epilogue)
        if (t + 1 < Sv) {
            int idx2 = ((bb * Sv + t + 1) * Hv + h) * Dv + j0;
            pk = *(const float2 *)&k_g[idx2];
            pv = *(const float2 *)&v_g[idx2];
            pq = *(const float2 *)&q_g[idx2];
        }

        // ---- F1o: acc1 = k@W1 (kept in regs all token); tgl_r; Kg; gelu
        f32x4 acc1 = mm64(Kp, W1T, w, c, q);
        {
            f32x4 a2 = mm64(TGp, LwR, w, c, q);
            if (q < 2) {
#pragma unroll
                for (int r = 0; r < 4; ++r) tgl_r[r] = a2[r] - c1_r;
            }
        }
        if (w == 0) {
            // Kg = K@K^T (rows/cols >=8 are zero via Kp padding); store -LR*Kg
            f32x4 kg = mm64(Kp, Kp, 0, c, q);
            if (q < 2) {
#pragma unroll
                for (int r = 0; r < 4; ++r) {
                    short hi, lo;
                    cvt1(-LR * kg[r], hi, lo);
                    KgT[c * 16 + 4 * q + r] = (unsigned short)hi;
                    KgT[c * 16 + 8 + 4 * q + r] = (unsigned short)lo;
                }
            }
        }
        if (q < 2) {
            int col = 16 * w + c;
            float gv[4];
#pragma unroll
            for (int r = 0; r < 4; ++r) {
                float g, dg;
                gelu_both(acc1[r] + b1_r, g, dg);
                gv[r] = g;
                gd_r[r] = dg;
            }
            unsigned h01, l01, h23, l23;
            cvt2(gv[0], gv[1], h01, l01);
            cvt2(gv[2], gv[3], h23, l23);
            Hp[(4 * q + 0) * 136 + col] = (unsigned short)h01;
            Hp[(4 * q + 1) * 136 + col] = (unsigned short)(h01 >> 16);
            Hp[(4 * q + 2) * 136 + col] = (unsigned short)h23;
            Hp[(4 * q + 3) * 136 + col] = (unsigned short)(h23 >> 16);
            Hp[(4 * q + 0) * 136 + 64 + col] = (unsigned short)l01;
            Hp[(4 * q + 1) * 136 + 64 + col] = (unsigned short)(l01 >> 16);
            Hp[(4 * q + 2) * 136 + 64 + col] = (unsigned short)l23;
            Hp[(4 * q + 3) * 136 + 64 + col] = (unsigned short)(l23 >> 16);
            uint2 hh, hl;
            hh.x = h01; hh.y = h23;
            hl.x = l01; hl.y = l23;
            *(uint2 *)&HT0[col * 16 + 4 * q] = hh;
            *(uint2 *)&HT0[col * 16 + 8 + 4 * q] = hl;
        }
        __syncthreads();

#pragma unroll 1
        for (int step = 0; step < 4; ++step) {
            const unsigned short *HTr = (step & 1) ? HT1 : HT0;
            unsigned short *HTw = (step & 1) ? HT0 : HT1;
            // F2: o = h@W2 + b2
            f32x4 acc = mm64(Hp, W2T, w, c, q);
            if (q < 2) {
                float bias = b2_s[16 * w + c];
#pragma unroll
                for (int r = 0; r < 4; ++r)
                    o_s[(4 * q + r) * 68 + 16 * w + c] = acc[r] + bias;
            }
            __syncthreads();
            // LN fwd (thread-mapped); xh kept in regs for LNb
            float xh0_r, xh1_r;
            {
                float2 xv = *(const float2 *)&o_s[bb * 68 + j0];
                float mu = red32(xv.x + xv.y) * (1.f / 64.f);
                float d0 = xv.x - mu, d1 = xv.y - mu;
                float var = red32(d0 * d0 + d1 * d1) * (1.f / 64.f);
                float rs = rsqrtf(var + 1e-5f);
                float xh0 = d0 * rs, xh1 = d1 * rs;
                float2 xw; xw.x = xh0; xw.y = xh1;
                *(float2 *)&xh_s[bb * 68 + j0] = xw;
                float z0 = xh0 * lg_s[j0] + lb_s[j0];
                float z1 = xh1 * lg_s[j0 + 1] + lb_s[j0 + 1];
                unsigned zh, zl;
                cvt2(z0, z1, zh, zl);
                *(unsigned *)&Zp[bb * 136 + j0] = zh;
                *(unsigned *)&Zp[bb * 136 + 64 + j0] = zl;
                if ((tid & 31) == 0) rstd_s[bb] = rs;
                xh0_r = xh0; xh1_r = xh1;
            }
            __syncthreads();
            // B1' (fused F3+B1): dz = SCALE * (z@G - tgl_r)
            acc = mm64(Zp, Gp, w, c, q);
            if (q < 2) {
                int col = 16 * w + c;
#pragma unroll
                for (int r = 0; r < 4; ++r)
                    o_s[(4 * q + r) * 68 + col] = (acc[r] - tgl_r[r]) * SCALE;
            }
            __syncthreads();
            // LN bwd (thread-mapped) -> do planes + doT
            {
                float2 dzv = *(const float2 *)&o_s[bb * 68 + j0];
                float dxh0 = dzv.x * lg_s[j0], dxh1 = dzv.y * lg_s[j0 + 1];
                float S1 = red32(dxh0 + dxh1) * (1.f / 64.f);
                float S2 = red32(dxh0 * xh0_r + dxh1 * xh1_r) * (1.f / 64.f);
                float rs = rstd_s[bb];
                float do0 = rs * (dxh0 - S1 - xh0_r * S2);
                float do1 = rs * (dxh1 - S1 - xh1_r * S2);
                unsigned dh, dl;
                cvt2(do0, do1, dh, dl);
                *(unsigned *)&DOp[bb * 136 + j0] = dh;
                *(unsigned *)&DOp[bb * 136 + 64 + j0] = dl;
                DOT[j0 * 16 + bb] = (unsigned short)dh;
                DOT[j0 * 16 + 8 + bb] = (unsigned short)dl;
                DOT[(j0 + 1) * 16 + bb] = (unsigned short)(dh >> 16);
                DOT[(j0 + 1) * 16 + 8 + bb] = (unsigned short)(dl >> 16);
            }
            __syncthreads();
            // B2+upd+F1' (single phase): prefetch stable operands into regs
            // first (A-frags KT/HTr/DOT, B-frags DOT/HTr, KgT) so their LDS
            // latency hides under mm64; then dh=do@W2^T; da->DAT; 3x reg-
            // based updW2; acc1 += (-LR*Kg)@da; gelu (step3 = final fwd h).
            bf16x8 zf8;
#pragma unroll
            for (int j = 0; j < 8; ++j) zf8[j] = 0;
            bf16x8 aK[4], aH[4], aD[4];
#pragma unroll
            for (int mt = 0; mt < 4; ++mt) {
                aK[mt] = *(const bf16x8 *)&KT[(16 * mt + c) * 16 + (q & 1) * 8];
                aH[mt] = *(const bf16x8 *)&HTr[(16 * mt + c) * 16 + (q & 1) * 8];
                aD[mt] = *(const bf16x8 *)&DOT[(16 * mt + c) * 16 + (q & 1) * 8];
            }
            bf16x8 bDO = zf8, bHT = zf8;
            if (q < 2) {
                bDO = *(const bf16x8 *)&DOT[(16 * w + c) * 16];
                bHT = *(const bf16x8 *)&HTr[(16 * w + c) * 16];
            } else if (q == 2) {
                bDO = *(const bf16x8 *)&DOT[(16 * w + c) * 16 + 8];
                bHT = *(const bf16x8 *)&HTr[(16 * w + c) * 16 + 8];
            }
            bf16x8 aKg = *(const bf16x8 *)&KgT[c * 16 + (q & 1) * 8];
            acc = mm64(DOp, W2R, w, c, q);
            {
                float b1sum = 0.f;
                if (q < 2) {
                    int col = 16 * w + c;
                    float da0 = acc[0] * gd_r[0];
                    float da1 = acc[1] * gd_r[1];
                    float da2 = acc[2] * gd_r[2];
                    float da3 = acc[3] * gd_r[3];
                    b1sum = da0 + da1 + da2 + da3;
                    unsigned h01, l01, h23, l23;
                    cvt2(da0, da1, h01, l01);
                    cvt2(da2, da3, h23, l23);
                    uint2 th, tl;
                    th.x = h01; th.y = h23;
                    tl.x = l01; tl.y = l23;
                    *(uint2 *)&DAT[col * 16 + 4 * q] = th;
                    *(uint2 *)&DAT[col * 16 + 8 + 4 * q] = tl;
                }
                b1sum += __shfl_xor(b1sum, 16);
                bf16x8 bDA = zf8;
                if (q < 2)
                    bDA = *(const bf16x8 *)&DAT[(16 * w + c) * 16];
                else if (q == 2)
                    bDA = *(const bf16x8 *)&DAT[(16 * w + c) * 16 + 8];
                updW2(aK, bDA, W1T, w, c, q);
                updW2(aH, bDO, W2T, w, c, q);
                updW2(aD, bHT, W2R, w, c, q);
                if (w == 2) {
                    bf16x8 oh_ = *(const bf16x8 *)&DOT[lane * 16];
                    bf16x8 ol_ = *(const bf16x8 *)&DOT[lane * 16 + 8];
                    float db2 = 0.f;
#pragma unroll
                    for (int j = 0; j < 8; ++j)
                        db2 += bf2f(oh_[j]) + bf2f(ol_[j]);
                    b2_s[lane] -= LR * db2;
                } else if (w == 3) {
                    float dlb = 0.f, dlg = 0.f;
#pragma unroll
                    for (int b = 0; b < 8; ++b) {
                        float dzv = o_s[b * 68 + lane];
                        dlb += dzv;
                        dlg += dzv * xh_s[b * 68 + lane];
                    }
                    lb_s[lane] -= LR * dlb;
                    lg_s[lane] -= LR * dlg;
                }
                // F1': incremental pre-activation + activation for next step
                acc1 = MFMA16(aKg, bDA, acc1);
                b1_r -= LR * b1sum;
                if (q < 2) {
                    int col = 16 * w + c;
                    if (step < 3) {
                        float gv[4];
#pragma unroll
                        for (int r = 0; r < 4; ++r) {
                            float g, dg;
                            gelu_both(acc1[r] + b1_r, g, dg);
                            gv[r] = g;
                            gd_r[r] = dg;
                        }
                        unsigned h01, l01, h23, l23;
                        cvt2(gv[0], gv[1], h01, l01);
                        cvt2(gv[2], gv[3], h23, l23);
                        Hp[(4 * q + 0) * 136 + col] = (unsigned short)h01;
                        Hp[(4 * q + 1) * 136 + col] = (unsigned short)(h01 >> 16);
                        Hp[(4 * q + 2) * 136 + col] = (unsigned short)h23;
                        Hp[(4 * q + 3) * 136 + col] = (unsigned short)(h23 >> 16);
                        Hp[(4 * q + 0) * 136 + 64 + col] = (unsigned short)l01;
                        Hp[(4 * q + 1) * 136 + 64 + col] = (unsigned short)(l01 >> 16);
                        Hp[(4 * q + 2) * 136 + 64 + col] = (unsigned short)l23;
                        Hp[(4 * q + 3) * 136 + 64 + col] = (unsigned short)(l23 >> 16);
                        uint2 hh, hl;
                        hh.x = h01; hh.y = h23;
                        hl.x = l01; hl.y = l23;
                        *(uint2 *)&HTw[col * 16 + 4 * q] = hh;
                        *(uint2 *)&HTw[col * 16 + 8 + 4 * q] = hl;
                    } else {
                        // final forward h (feeds F2fin); no HT/gd needed
                        float gv[4];
#pragma unroll
                        for (int r = 0; r < 4; ++r)
                            gv[r] = gelu_f(acc1[r] + b1_r);
                        unsigned h01, l01, h23, l23;
                        cvt2(gv[0], gv[1], h01, l01);
                        cvt2(gv[2], gv[3], h23, l23);
                        Hp[(4 * q + 0) * 136 + col] = (unsigned short)h01;
                        Hp[(4 * q + 1) * 136 + col] = (unsigned short)(h01 >> 16);
                        Hp[(4 * q + 2) * 136 + col] = (unsigned short)h23;
                        Hp[(4 * q + 3) * 136 + col] = (unsigned short)(h23 >> 16);
                        Hp[(4 * q + 0) * 136 + 64 + col] = (unsigned short)l01;
                        Hp[(4 * q + 1) * 136 + 64 + col] = (unsigned short)(l01 >> 16);
                        Hp[(4 * q + 2) * 136 + 64 + col] = (unsigned short)l23;
                        Hp[(4 * q + 3) * 136 + 64 + col] = (unsigned short)(l23 >> 16);
                    }
                }
            }
            __syncthreads();
        }

        // ---- F2fin: o = h_final@W2 + b2 ; stage token t+1 (Kp/KT/TGp)
        f32x4 acc = mm64(Hp, W2T, w, c, q);
        if (q < 2) {
            float bias = b2_s[16 * w + c];
#pragma unroll
            for (int r = 0; r < 4; ++r)
                o_s[(4 * q + r) * 68 + 16 * w + c] = acc[r] + bias;
        }
        if (t + 1 < Sv) {
            unsigned khw, klw;
            cvt2(pk.x, pk.y, khw, klw);
            *(unsigned *)&Kp[bb * 136 + j0] = khw;
            *(unsigned *)&Kp[bb * 136 + 64 + j0] = klw;
            KT[j0 * 16 + bb] = (unsigned short)khw;
            KT[j0 * 16 + 8 + bb] = (unsigned short)klw;
            KT[(j0 + 1) * 16 + bb] = (unsigned short)(khw >> 16);
            KT[(j0 + 1) * 16 + 8 + bb] = (unsigned short)(klw >> 16);
            unsigned thw, tlw;
            cvt2(pv.x - pk.x, pv.y - pk.y, thw, tlw);
            *(unsigned *)&TGp[bb * 136 + j0] = thw;
            *(unsigned *)&TGp[bb * 136 + 64 + j0] = tlw;
        }
        __syncthreads();
        // epilogue: LN(lg,lb) -> LN(ttt_g,ttt_b) -> out = q + z2
        // (no trailing barrier: F1o's end-barrier orders the o_s reuse)
        {
            float2 xv = *(const float2 *)&o_s[bb * 68 + j0];
            float mu = red32(xv.x + xv.y) * (1.f / 64.f);
            float d0 = xv.x - mu, d1 = xv.y - mu;
            float var = red32(d0 * d0 + d1 * d1) * (1.f / 64.f);
            float rs = rsqrtf(var + 1e-5f);
            float z0 = d0 * rs * lg_s[j0] + lb_s[j0];
            float z1 = d1 * rs * lg_s[j0 + 1] + lb_s[j0 + 1];
            float mu2 = red32(z0 + z1) * (1.f / 64.f);
            float e0 = z0 - mu2, e1 = z1 - mu2;
            float var2 = red32(e0 * e0 + e1 * e1) * (1.f / 64.f);
            float rs2 = rsqrtf(var2 + 1e-5f);
            float z20 = e0 * rs2 * tG_s[j0] + tB_s[j0];
            float z21 = e1 * rs2 * tG_s[j0 + 1] + tB_s[j0 + 1];
            int idx = ((bb * Sv + t) * Hv + h) * Dv + j0;
            float2 ov;
            ov.x = q_cur.x + z20;
            ov.y = q_cur.y + z21;
            *(float2 *)&out_g[idx] = ov;
            q_cur = pq;
        }
    }
}

// ---------------------------------------------------------------------------
// fp32 GEMM: C[M,N] = A[M,K] @ B[K,N]; mode 1: C = gelu(acc) * gate_ln
// ---------------------------------------------------------------------------
__global__ __launch_bounds__(256) void gemm_f32(
    const float *__restrict__ A, const float *__restrict__ B,
    float *__restrict__ C, const float *__restrict__ gate_ln,
    int M, int N, int K, int mode) {
    __shared__ float As[16][68];
    __shared__ float Bs[16][64];
    const int tid = threadIdx.x;
    const int tx = tid & 15, ty = tid >> 4;
    const int bm = blockIdx.y * 64, bn = blockIdx.x * 64;

    float acc[4][4] = {};
    for (int k0 = 0; k0 < K; k0 += 16) {
        {
            int r = tid >> 2, kk = (tid & 3) * 4;
            float4 av = *(const float4 *)(A + (long)(bm + r) * K + k0 + kk);
            As[kk + 0][r] = av.x;
            As[kk + 1][r] = av.y;
            As[kk + 2][r] = av.z;
            As[kk + 3][r] = av.w;
            int rr = tid >> 4, cc = (tid & 15) * 4;
            float4 bv = *(const float4 *)(B + (long)(k0 + rr) * N + bn + cc);
            *(float4 *)&Bs[rr][cc] = bv;
        }
        __syncthreads();
#pragma unroll
        for (int kk = 0; kk < 16; ++kk) {
            float4 a4 = *(float4 *)&As[kk][ty * 4];
            float4 b4 = *(float4 *)&Bs[kk][tx * 4];
            float a[4] = {a4.x, a4.y, a4.z, a4.w};
            float b[4] = {b4.x, b4.y, b4.z, b4.w};
#pragma unroll
            for (int i = 0; i < 4; ++i)
#pragma unroll
                for (int j = 0; j < 4; ++j) acc[i][j] += a[i] * b[j];
        }
        __syncthreads();
    }
#pragma unroll
    for (int i = 0; i < 4; ++i) {
        int row = bm + ty * 4 + i;
        float4 out;
        float v[4];
#pragma unroll
        for (int j = 0; j < 4; ++j) {
            float val = acc[i][j];
            if (mode == 1) {
                int col = bn + tx * 4 + j;
                val = gelu_f(val) * gate_ln[(long)row * N + col];
            }
            v[j] = val;
        }
        out.x = v[0]; out.y = v[1]; out.z = v[2]; out.w = v[3];
        *(float4 *)(C + (long)row * N + bn + tx * 4) = out;
    }
}

// ---------------------------------------------------------------------------
// Row LayerNorm over 1024 (post-scan, pn_g / pn_b)
// ---------------------------------------------------------------------------
__global__ __launch_bounds__(256) void row_ln(const float *__restrict__ in,
                                              float *__restrict__ out,
                                              const float *__restrict__ g,
                                              const float *__restrict__ b) {
    __shared__ float sred[4], s2red[4];
    const int row = blockIdx.x;
    const int tid = threadIdx.x;
    const float *x = in + (long)row * 1024;
    float4 v = *(const float4 *)(x + tid * 4);
    float s = v.x + v.y + v.z + v.w;
    float s2 = v.x * v.x + v.y * v.y + v.z * v.z + v.w * v.w;
#pragma unroll
    for (int m = 1; m <= 32; m <<= 1) {
        s += __shfl_xor(s, m);
        s2 += __shfl_xor(s2, m);
    }
    if ((tid & 63) == 0) {
        sred[tid >> 6] = s;
        s2red[tid >> 6] = s2;
    }
    __syncthreads();
    float S = sred[0] + sred[1] + sred[2] + sred[3];
    float S2 = s2red[0] + s2red[1] + s2red[2] + s2red[3];
    float mu = S * (1.f / 1024.f);
    float var = S2 * (1.f / 1024.f) - mu * mu;
    float rs = rsqrtf(var + 1e-5f);
    float o[4] = {v.x, v.y, v.z, v.w};
    float4 ov;
    float r[4];
#pragma unroll
    for (int i = 0; i < 4; ++i) {
        int col = tid * 4 + i;
        r[i] = (o[i] - mu) * rs * g[col] + b[col];
    }
    ov.x = r[0]; ov.y = r[1]; ov.z = r[2]; ov.w = r[3];
    *(float4 *)(out + (long)row * 1024 + tid * 4) = ov;
}

// ---------------------------------------------------------------------------
// Launch
// ---------------------------------------------------------------------------
extern "C" void kernel_launch(void *const *d_in, const int *in_sizes, int n_in,
                              void *d_out, int out_size, void *d_ws,
                              size_t ws_size, hipStream_t stream) {
    const float *x = (const float *)d_in[0];
    const float *wq = (const float *)d_in[1];
    const float *wk = (const float *)d_in[2];
    const float *wv = (const float *)d_in[3];
    const float *fw_w1 = (const float *)d_in[4];
    const float *fw_b1 = (const float *)d_in[5];
    const float *fw_w2 = (const float *)d_in[6];
    const float *fw_b2 = (const float *)d_in[7];
    const float *fw_lng = (const float *)d_in[8];
    const float *fw_lnb = (const float *)d_in[9];
    const float *loss_w = (const float *)d_in[10];
    const float *loss_b = (const float *)d_in[11];
    const float *ttt_g = (const float *)d_in[12];
    const float *ttt_b = (const float *)d_in[13];
    const float *wo = (const float *)d_in[14];
    const float *wg = (const float *)d_in[15];
    const float *pn_g = (const float *)d_in[16];
    const float *pn_b = (const float *)d_in[17];

    const long MAT = 2048L * 1024L;
    float *q_ws = (float *)d_ws;
    float *k_ws = q_ws + MAT;
    float *v_ws = k_ws + MAT;
    float *out_ws = v_ws + MAT;
    float *ln_ws = k_ws;       // reuse (k dead after scan)
    float *gated_ws = v_ws;    // reuse (v dead after scan)

    dim3 gg(1024 / 64, 2048 / 64), bt(256);
    hipLaunchKernelGGL(gemm_f32, gg, bt, 0, stream, x, wq, q_ws,
                       (const float *)nullptr, 2048, 1024, 1024, 0);
    hipLaunchKernelGGL(gemm_f32, gg, bt, 0, stream, x, wk, k_ws,
                       (const float *)nullptr, 2048, 1024, 1024, 0);
    hipLaunchKernelGGL(gemm_f32, gg, bt, 0, stream, x, wv, v_ws,
                       (const float *)nullptr, 2048, 1024, 1024, 0);

    (void)hipFuncSetAttribute((const void *)ttt_scan,
                              hipFuncAttributeMaxDynamicSharedMemorySize,
                              LDS_BYTES);
    hipLaunchKernelGGL(ttt_scan, dim3(16), dim3(256), LDS_BYTES, stream,
                       q_ws, k_ws, v_ws, out_ws, fw_w1, fw_b1, fw_w2, fw_b2,
                       fw_lng, fw_lnb, loss_w, loss_b, ttt_g, ttt_b);

    hipLaunchKernelGGL(row_ln, dim3(2048), dim3(256), 0, stream, out_ws, ln_ws,
                       pn_g, pn_b);
    hipLaunchKernelGGL(gemm_f32, gg, bt, 0, stream, x, wg, gated_ws, ln_ws,
                       2048, 1024, 1024, 1);
    hipLaunchKernelGGL(gemm_f32, gg, bt, 0, stream, gated_ws, wo,
                       (float *)d_out, (const float *)nullptr, 2048, 1024,
                       1024, 0);
}